// Round 1
// baseline (474.826 us; speedup 1.0000x reference)
//
#include <hip/hip_runtime.h>
#include <stdint.h>

typedef unsigned short u16;
typedef __attribute__((ext_vector_type(8))) short short8;
typedef __attribute__((ext_vector_type(4))) float f32x4;

#define GPTR(p) ((const __attribute__((address_space(1))) void*)(p))
#define SPTR(p) ((__attribute__((address_space(3))) void*)(p))
#define GLDS16(g, l) __builtin_amdgcn_global_load_lds(GPTR(g), SPTR(l), 16, 0, 0)

static __device__ __forceinline__ float bf2f(u16 u) {
  union { unsigned int i; float f; } c; c.i = ((unsigned int)u) << 16; return c.f;
}
static __device__ __forceinline__ u16 f2bf(float f) {
  union { float f; unsigned int u; } c; c.f = f;
  unsigned int r = 0x7fffu + ((c.u >> 16) & 1u);
  return (u16)((c.u + r) >> 16);
}
// chunk swizzle for 64B rows (4x16B chunks): involution, spreads banks
static __device__ __forceinline__ int swz4(int row, int c) { return c ^ ((row >> 1) & 3); }

// ---------------- LayerNorm: f32 (rows of 1024) -> bf16 ----------------
__global__ __launch_bounds__(256) void ln_kernel(
    const float* __restrict__ x, const float* __restrict__ ctx,
    const float* __restrict__ g, const float* __restrict__ b,
    const float* __restrict__ cg, const float* __restrict__ cb,
    u16* __restrict__ xn, u16* __restrict__ cn)
{
  const int row = blockIdx.x;
  const float* src; const float* gg; const float* bb; u16* dst;
  if (row < 4096) { src = x + (size_t)row * 1024; gg = g;  bb = b;  dst = xn + (size_t)row * 1024; }
  else            { src = ctx + (size_t)(row - 4096) * 1024; gg = cg; bb = cb; dst = cn + (size_t)(row - 4096) * 1024; }
  const int t = threadIdx.x;
  float4 v = *(const float4*)&src[t * 4];
  float s  = v.x + v.y + v.z + v.w;
  float s2 = v.x * v.x + v.y * v.y + v.z * v.z + v.w * v.w;
  #pragma unroll
  for (int off = 1; off < 64; off <<= 1) { s += __shfl_xor(s, off); s2 += __shfl_xor(s2, off); }
  __shared__ float ls[4], ls2[4];
  const int w = t >> 6;
  if ((t & 63) == 0) { ls[w] = s; ls2[w] = s2; }
  __syncthreads();
  s  = ls[0] + ls[1] + ls[2] + ls[3];
  s2 = ls2[0] + ls2[1] + ls2[2] + ls2[3];
  const float mu   = s * (1.0f / 1024.0f);
  const float var  = s2 * (1.0f / 1024.0f) - mu * mu;
  const float rstd = rsqrtf(var + 1e-5f);
  float xv[4] = { v.x, v.y, v.z, v.w };
  u16 o[4];
  #pragma unroll
  for (int i = 0; i < 4; ++i)
    o[i] = f2bf((xv[i] - mu) * rstd * gg[t * 4 + i] + bb[t * 4 + i]);
  uint2 pv;
  pv.x = (unsigned)o[0] | ((unsigned)o[1] << 16);
  pv.y = (unsigned)o[2] | ((unsigned)o[3] << 16);
  *(uint2*)&dst[t * 4] = pv;
}

// ---------------- transpose+convert: f32 (R,C) -> bf16 (C,R) ----------------
// grid: (C/64, R/64), block 256
__global__ __launch_bounds__(256) void transpose_k(
    const float* __restrict__ in, u16* __restrict__ out, int R, int C)
{
  __shared__ float tile[64][65];
  const int c0 = blockIdx.x * 64, r0 = blockIdx.y * 64;
  const int t = threadIdx.x;
  const int tr = t >> 4, tc = (t & 15) * 4;
  #pragma unroll
  for (int i = 0; i < 4; ++i) {
    int r = tr + i * 16;
    float4 v = *(const float4*)&in[(size_t)(r0 + r) * C + c0 + tc];
    tile[r][tc + 0] = v.x; tile[r][tc + 1] = v.y; tile[r][tc + 2] = v.z; tile[r][tc + 3] = v.w;
  }
  __syncthreads();
  #pragma unroll
  for (int i = 0; i < 2; ++i) {
    int c  = (t >> 3) + i * 32;
    int rb = (t & 7) * 8;
    union { u16 s[8]; uint4 v; } pk;
    #pragma unroll
    for (int u = 0; u < 8; ++u) pk.s[u] = f2bf(tile[rb + u][c]);
    *(uint4*)&out[(size_t)(c0 + c) * R + r0 + rb] = pk.v;
  }
}

// ---------------- GEMM: C(MxN) = A(MxK,row) * BT(NxK,row)^T ----------------
// 128x128 tile, BK=32, 4 waves (2x2), 16x16x32 bf16 MFMA. M,N mult of 128, K mult of 32.
// MODE 0: bf16 store with scale; MODE 1: f32 store; MODE 2: f32 +=
template<int MODE>
__global__ __launch_bounds__(256) void gemm_bt(
    const u16* __restrict__ A, const u16* __restrict__ BT, void* __restrict__ C,
    int M, int N, int K, float scale)
{
  __shared__ u16 As[128 * 32];
  __shared__ u16 Bs[128 * 32];
  const int bm = blockIdx.y, bn = blockIdx.x;
  const int t = threadIdx.x;
  const int w = t >> 6, lane = t & 63;
  const int wr = w >> 1, wc = w & 1;
  const int lr = lane & 15, lkc = lane >> 4; // frag row / k-chunk

  f32x4 acc[4][4];
  const f32x4 z4 = { 0.f, 0.f, 0.f, 0.f };
  #pragma unroll
  for (int mi = 0; mi < 4; ++mi)
    #pragma unroll
    for (int ni = 0; ni < 4; ++ni) acc[mi][ni] = z4;

  // staging: chunk i (0..511): row=i>>2, dest chunk i&3 holds logical chunk swz4(row,i&3)
  const int i0 = t, i1 = t + 256;
  const int r0 = i0 >> 2, k0 = swz4(r0, i0 & 3) * 8;
  const int r1 = i1 >> 2, k1 = swz4(r1, i1 & 3) * 8;
  const u16* a0 = A + (size_t)(bm * 128 + r0) * K + k0;
  const u16* a1 = A + (size_t)(bm * 128 + r1) * K + k1;
  const u16* b0 = BT + (size_t)(bn * 128 + r0) * K + k0;
  const u16* b1 = BT + (size_t)(bn * 128 + r1) * K + k1;
  u16* As0 = As + (size_t)w * 512;        // wave-uniform LDS bases (HW adds lane*16B)
  u16* As1 = As + (size_t)(w + 4) * 512;
  u16* Bs0 = Bs + (size_t)w * 512;
  u16* Bs1 = Bs + (size_t)(w + 4) * 512;

  const int nk = K >> 5;
  for (int kt = 0; kt < nk; ++kt) {
    __syncthreads();
    GLDS16(a0, As0); GLDS16(a1, As1); GLDS16(b0, Bs0); GLDS16(b1, Bs1);
    a0 += 32; a1 += 32; b0 += 32; b1 += 32;
    __syncthreads();
    short8 af[4], bf[4];
    #pragma unroll
    for (int mi = 0; mi < 4; ++mi) {
      int row = wr * 64 + mi * 16 + lr;
      af[mi] = *(const short8*)&As[row * 32 + swz4(row, lkc) * 8];
    }
    #pragma unroll
    for (int ni = 0; ni < 4; ++ni) {
      int row = wc * 64 + ni * 16 + lr;
      bf[ni] = *(const short8*)&Bs[row * 32 + swz4(row, lkc) * 8];
    }
    #pragma unroll
    for (int mi = 0; mi < 4; ++mi)
      #pragma unroll
      for (int ni = 0; ni < 4; ++ni)
        acc[mi][ni] = __builtin_amdgcn_mfma_f32_16x16x32_bf16(af[mi], bf[ni], acc[mi][ni], 0, 0, 0);
  }

  const int row0 = bm * 128 + wr * 64, col0 = bn * 128 + wc * 64;
  const int rsub = (lane >> 4) * 4;
  #pragma unroll
  for (int mi = 0; mi < 4; ++mi) {
    #pragma unroll
    for (int ni = 0; ni < 4; ++ni) {
      #pragma unroll
      for (int r = 0; r < 4; ++r) {
        const size_t idx = (size_t)(row0 + mi * 16 + rsub + r) * N + (col0 + ni * 16 + lr);
        const float v = acc[mi][ni][r] * scale;
        if constexpr (MODE == 0)      ((u16*)C)[idx] = f2bf(v);
        else if constexpr (MODE == 1) ((float*)C)[idx] = v;
        else                          ((float*)C)[idx] += v;
      }
    }
  }
}

// ---------------- flash cross-attention (multi-query: 1 KV head) ----------------
// q: (B*N, 1024) bf16 pre-scaled, head h at cols h*64..+63
// kv: (B*J, 128) bf16: K at [0..63], V at [64..127]
// o: (B*N, 1024) bf16
// grid (N/64, H, B), block 256 (4 waves x 16 q-rows), JBLK=64
__global__ __launch_bounds__(256) void attn_kernel(
    const u16* __restrict__ q, const u16* __restrict__ kv, u16* __restrict__ o)
{
  __shared__ u16 Ks[64 * 64];   // [j][d], rows 128B, chunk-swizzled by (row&7)
  __shared__ u16 Vs[64 * 64];   // [d][j] transposed, swizzled
  __shared__ u16 Ps[4][16 * 64];// per-wave P tile, swizzled
  const int b = blockIdx.z, h = blockIdx.y, qb = blockIdx.x;
  const int t = threadIdx.x, w = t >> 6, lane = t & 63;
  const int lr = lane & 15, lk8 = (lane >> 4) * 8;

  const size_t qrow = (size_t)b * 2048 + qb * 64 + w * 16 + lr;
  const short8 qa0 = *(const short8*)&q[qrow * 1024 + h * 64 + lk8];
  const short8 qa1 = *(const short8*)&q[qrow * 1024 + h * 64 + 32 + lk8];

  float m0[4], l0[4];
  f32x4 oacc[4];
  const f32x4 z4 = { 0.f, 0.f, 0.f, 0.f };
  #pragma unroll
  for (int r = 0; r < 4; ++r) { m0[r] = -1e30f; l0[r] = 0.f; }
  #pragma unroll
  for (int dt = 0; dt < 4; ++dt) oacc[dt] = z4;

  const size_t kvb = (size_t)b * 2048 * 128;
  // K staging: chunk i: row=i>>3, dest chunk i&7 holds logical chunk (i&7)^(row&7)
  const int iK0 = t, iK1 = t + 256;
  const int kr0 = iK0 >> 3, kc0 = ((iK0 & 7) ^ (kr0 & 7)) * 8;
  const int kr1 = iK1 >> 3, kc1 = ((iK1 & 7) ^ (kr1 & 7)) * 8;
  u16* Kd0 = Ks + (size_t)w * 512;
  u16* Kd1 = Ks + (size_t)(w + 4) * 512;

  for (int jt = 0; jt < 32; ++jt) {
    __syncthreads();
    GLDS16(&kv[kvb + (size_t)(jt * 64 + kr0) * 128 + kc0], Kd0);
    GLDS16(&kv[kvb + (size_t)(jt * 64 + kr1) * 128 + kc1], Kd1);
    // V transposed staging (coalesced global read, swizzled LDS scatter)
    #pragma unroll
    for (int c = 0; c < 2; ++c) {
      const int i = c * 256 + t;
      const int vj = i >> 3, vd0 = (i & 7) * 8;
      const short8 vv = *(const short8*)&kv[kvb + (size_t)(jt * 64 + vj) * 128 + 64 + vd0];
      #pragma unroll
      for (int u = 0; u < 8; ++u) {
        const int d = vd0 + u;
        const int byteoff = d * 128 + ((2 * vj) ^ ((d & 7) << 4));
        Vs[byteoff >> 1] = (u16)vv[u];
      }
    }
    __syncthreads();

    // QK^T: sim[qrow][j], 4 j16-tiles, accumulate over 2 d-chunks
    f32x4 s[4];
    #pragma unroll
    for (int j16 = 0; j16 < 4; ++j16) s[j16] = z4;
    #pragma unroll
    for (int j16 = 0; j16 < 4; ++j16) {
      const int row = j16 * 16 + lr;
      const int base = row * 128;
      const short8 kb0 = *(const short8*)((const char*)Ks + base + ((lk8 * 2)      ^ ((row & 7) << 4)));
      const short8 kb1 = *(const short8*)((const char*)Ks + base + ((64 + lk8 * 2) ^ ((row & 7) << 4)));
      s[j16] = __builtin_amdgcn_mfma_f32_16x16x32_bf16(qa0, kb0, s[j16], 0, 0, 0);
      s[j16] = __builtin_amdgcn_mfma_f32_16x16x32_bf16(qa1, kb1, s[j16], 0, 0, 0);
    }

    // online softmax (rows (lane>>4)*4+r live in 16-lane groups)
    float mt[4];
    #pragma unroll
    for (int r = 0; r < 4; ++r)
      mt[r] = fmaxf(fmaxf(s[0][r], s[1][r]), fmaxf(s[2][r], s[3][r]));
    #pragma unroll
    for (int off = 1; off < 16; off <<= 1)
      #pragma unroll
      for (int r = 0; r < 4; ++r) mt[r] = fmaxf(mt[r], __shfl_xor(mt[r], off));
    float alpha[4], lsum[4];
    #pragma unroll
    for (int r = 0; r < 4; ++r) {
      const float nm = fmaxf(m0[r], mt[r]);
      alpha[r] = __expf(m0[r] - nm);
      m0[r] = nm;
      lsum[r] = 0.f;
    }
    const int rsub = (lane >> 4) * 4;
    #pragma unroll
    for (int j16 = 0; j16 < 4; ++j16) {
      #pragma unroll
      for (int r = 0; r < 4; ++r) {
        const float p = __expf(s[j16][r] - m0[r]);
        lsum[r] += p;
        const int prow = rsub + r;
        const int pbyte = prow * 128 + ((2 * (j16 * 16 + lr)) ^ ((prow & 7) << 4));
        Ps[w][pbyte >> 1] = f2bf(p);
      }
    }
    #pragma unroll
    for (int off = 1; off < 16; off <<= 1)
      #pragma unroll
      for (int r = 0; r < 4; ++r) lsum[r] += __shfl_xor(lsum[r], off);
    #pragma unroll
    for (int r = 0; r < 4; ++r) l0[r] = l0[r] * alpha[r] + lsum[r];
    #pragma unroll
    for (int dt = 0; dt < 4; ++dt)
      #pragma unroll
      for (int r = 0; r < 4; ++r) oacc[dt][r] *= alpha[r];

    // PV: O[qrow][d] += P[qrow][j] * Vt[d][j]
    #pragma unroll
    for (int jc = 0; jc < 2; ++jc) {
      const int pb = lr * 128 + ((jc * 64 + lk8 * 2) ^ ((lr & 7) << 4));
      const short8 pa = *(const short8*)((const char*)Ps[w] + pb);
      #pragma unroll
      for (int dt = 0; dt < 4; ++dt) {
        const int vrow = dt * 16 + lr;
        const int vb = vrow * 128 + ((jc * 64 + lk8 * 2) ^ ((vrow & 7) << 4));
        const short8 vf = *(const short8*)((const char*)Vs + vb);
        oacc[dt] = __builtin_amdgcn_mfma_f32_16x16x32_bf16(pa, vf, oacc[dt], 0, 0, 0);
      }
    }
  }

  const int rsub = (lane >> 4) * 4;
  #pragma unroll
  for (int r = 0; r < 4; ++r) {
    const float inv = 1.0f / l0[r];
    const size_t orow = (size_t)b * 2048 + qb * 64 + w * 16 + rsub + r;
    #pragma unroll
    for (int dt = 0; dt < 4; ++dt)
      o[orow * 1024 + h * 64 + dt * 16 + lr] = f2bf(oacc[dt][r] * inv);
  }
}

// ---------------- silu(gate)*a : ff (4096,8192) -> h (4096,4096) ----------------
__global__ __launch_bounds__(256) void silu_kernel(const u16* __restrict__ ff, u16* __restrict__ h)
{
  const size_t i = (size_t)blockIdx.x * 256 + threadIdx.x; // one 8-elem chunk
  const size_t row = i >> 9;
  const size_t c8 = (i & 511) * 8;
  const short8 av = *(const short8*)&ff[row * 8192 + c8];
  const short8 gv = *(const short8*)&ff[row * 8192 + 4096 + c8];
  union { u16 s[8]; uint4 v; } pk;
  #pragma unroll
  for (int u = 0; u < 8; ++u) {
    const float gg = bf2f((u16)gv[u]);
    const float aa = bf2f((u16)av[u]);
    const float sg = gg / (1.0f + __expf(-gg));
    pk.s[u] = f2bf(sg * aa);
  }
  *(uint4*)&h[row * 4096 + c8] = pk.v;
}

extern "C" void kernel_launch(void* const* d_in, const int* in_sizes, int n_in,
                              void* d_out, int out_size, void* d_ws, size_t ws_size,
                              hipStream_t stream)
{
  const float* x    = (const float*)d_in[0];
  const float* ctx  = (const float*)d_in[1];
  const float* ng   = (const float*)d_in[2];
  const float* nb   = (const float*)d_in[3];
  const float* cg   = (const float*)d_in[4];
  const float* cb   = (const float*)d_in[5];
  const float* Wq   = (const float*)d_in[6];
  const float* Wkv  = (const float*)d_in[7];
  const float* Wo   = (const float*)d_in[8];
  const float* Wff1 = (const float*)d_in[9];
  const float* Wff2 = (const float*)d_in[10];

  u16* p = (u16*)d_ws;
  u16* WqT   = p; p += (size_t)1024 * 1024;
  u16* WkvT  = p; p += (size_t)128 * 1024;
  u16* WoT   = p; p += (size_t)1024 * 1024;
  u16* Wff1T = p; p += (size_t)8192 * 1024;
  u16* Wff2T = p; p += (size_t)1024 * 4096;
  u16* xn    = p; p += (size_t)4096 * 1024;
  u16* cn    = p; p += (size_t)4096 * 1024;
  u16* qbuf  = p; p += (size_t)4096 * 1024;
  u16* kvbuf = p; p += (size_t)4096 * 128;
  u16* ao    = p; p += (size_t)4096 * 1024;
  u16* ffb   = p; p += (size_t)4096 * 8192;
  u16* hb    = p; p += (size_t)4096 * 4096;
  (void)in_sizes; (void)n_in; (void)out_size; (void)ws_size;

  ln_kernel<<<8192, 256, 0, stream>>>(x, ctx, ng, nb, cg, cb, xn, cn);

  transpose_k<<<dim3(16, 16), 256, 0, stream>>>(Wq,   WqT,   1024, 1024);
  transpose_k<<<dim3(2, 16),  256, 0, stream>>>(Wkv,  WkvT,  1024, 128);
  transpose_k<<<dim3(16, 16), 256, 0, stream>>>(Wo,   WoT,   1024, 1024);
  transpose_k<<<dim3(128, 16),256, 0, stream>>>(Wff1, Wff1T, 1024, 8192);
  transpose_k<<<dim3(16, 64), 256, 0, stream>>>(Wff2, Wff2T, 4096, 1024);

  // q = xn @ Wq * DH^-0.5   (4096x1024x1024)
  gemm_bt<0><<<dim3(8, 32), 256, 0, stream>>>(xn, WqT, qbuf, 4096, 1024, 1024, 0.125f);
  // kv = cn @ Wkv           (4096x128x1024)
  gemm_bt<0><<<dim3(1, 32), 256, 0, stream>>>(cn, WkvT, kvbuf, 4096, 128, 1024, 1.0f);
  // attention
  attn_kernel<<<dim3(32, 16, 2), 256, 0, stream>>>(qbuf, kvbuf, ao);
  // out = ao @ Wo           (4096x1024x1024), f32 store
  gemm_bt<1><<<dim3(8, 32), 256, 0, stream>>>(ao, WoT, d_out, 4096, 1024, 1024, 1.0f);
  // ff = xn @ Wff1          (4096x8192x1024)
  gemm_bt<0><<<dim3(64, 32), 256, 0, stream>>>(xn, Wff1T, ffb, 4096, 8192, 1024, 1.0f);
  // h = silu(gate)*a
  silu_kernel<<<8192, 256, 0, stream>>>(ffb, hb);
  // out += h @ Wff2         (4096x1024x4096), f32 accumulate
  gemm_bt<2><<<dim3(8, 32), 256, 0, stream>>>(hb, Wff2T, d_out, 4096, 1024, 4096, 1.0f);
}

// Round 2
// 403.003 us; speedup vs baseline: 1.1782x; 1.1782x over previous
//
#include <hip/hip_runtime.h>
#include <stdint.h>

typedef unsigned short u16;
typedef __attribute__((ext_vector_type(8))) short short8;
typedef __attribute__((ext_vector_type(4))) float f32x4;
typedef __attribute__((ext_vector_type(16))) float f32x16;

#define GPTR(p) ((const __attribute__((address_space(1))) void*)(p))
#define SPTR(p) ((__attribute__((address_space(3))) void*)(p))
#define GLDS16(g, l) __builtin_amdgcn_global_load_lds(GPTR(g), SPTR(l), 16, 0, 0)

static __device__ __forceinline__ float bf2f(u16 u) {
  union { unsigned int i; float f; } c; c.i = ((unsigned int)u) << 16; return c.f;
}
static __device__ __forceinline__ u16 f2bf(float f) {
  union { float f; unsigned int u; } c; c.f = f;
  unsigned int r = 0x7fffu + ((c.u >> 16) & 1u);
  return (u16)((c.u + r) >> 16);
}
static __device__ __forceinline__ unsigned cvtpk(float a, float b) {
  unsigned r;
  asm volatile("v_cvt_pk_bf16_f32 %0, %1, %2" : "=v"(r) : "v"(a), "v"(b));
  return r;
}
// chunk swizzle for 64B rows (4x16B chunks): involution, spreads banks
static __device__ __forceinline__ int swz4(int row, int c) { return c ^ ((row >> 1) & 3); }

// ---------------- LayerNorm: f32 (rows of 1024) -> bf16 ----------------
__global__ __launch_bounds__(256) void ln_kernel(
    const float* __restrict__ x, const float* __restrict__ ctx,
    const float* __restrict__ g, const float* __restrict__ b,
    const float* __restrict__ cg, const float* __restrict__ cb,
    u16* __restrict__ xn, u16* __restrict__ cn)
{
  const int row = blockIdx.x;
  const float* src; const float* gg; const float* bb; u16* dst;
  if (row < 4096) { src = x + (size_t)row * 1024; gg = g;  bb = b;  dst = xn + (size_t)row * 1024; }
  else            { src = ctx + (size_t)(row - 4096) * 1024; gg = cg; bb = cb; dst = cn + (size_t)(row - 4096) * 1024; }
  const int t = threadIdx.x;
  float4 v = *(const float4*)&src[t * 4];
  float s  = v.x + v.y + v.z + v.w;
  float s2 = v.x * v.x + v.y * v.y + v.z * v.z + v.w * v.w;
  #pragma unroll
  for (int off = 1; off < 64; off <<= 1) { s += __shfl_xor(s, off); s2 += __shfl_xor(s2, off); }
  __shared__ float ls[4], ls2[4];
  const int w = t >> 6;
  if ((t & 63) == 0) { ls[w] = s; ls2[w] = s2; }
  __syncthreads();
  s  = ls[0] + ls[1] + ls[2] + ls[3];
  s2 = ls2[0] + ls2[1] + ls2[2] + ls2[3];
  const float mu   = s * (1.0f / 1024.0f);
  const float var  = s2 * (1.0f / 1024.0f) - mu * mu;
  const float rstd = rsqrtf(var + 1e-5f);
  float xv[4] = { v.x, v.y, v.z, v.w };
  u16 o[4];
  #pragma unroll
  for (int i = 0; i < 4; ++i)
    o[i] = f2bf((xv[i] - mu) * rstd * gg[t * 4 + i] + bb[t * 4 + i]);
  uint2 pv;
  pv.x = (unsigned)o[0] | ((unsigned)o[1] << 16);
  pv.y = (unsigned)o[2] | ((unsigned)o[3] << 16);
  *(uint2*)&dst[t * 4] = pv;
}

// ---------------- transpose+convert: f32 (R,C) -> bf16 (C,R) ----------------
// grid: (C/64, R/64), block 256
__global__ __launch_bounds__(256) void transpose_k(
    const float* __restrict__ in, u16* __restrict__ out, int R, int C)
{
  __shared__ float tile[64][65];
  const int c0 = blockIdx.x * 64, r0 = blockIdx.y * 64;
  const int t = threadIdx.x;
  const int tr = t >> 4, tc = (t & 15) * 4;
  #pragma unroll
  for (int i = 0; i < 4; ++i) {
    int r = tr + i * 16;
    float4 v = *(const float4*)&in[(size_t)(r0 + r) * C + c0 + tc];
    tile[r][tc + 0] = v.x; tile[r][tc + 1] = v.y; tile[r][tc + 2] = v.z; tile[r][tc + 3] = v.w;
  }
  __syncthreads();
  #pragma unroll
  for (int i = 0; i < 2; ++i) {
    int c  = (t >> 3) + i * 32;
    int rb = (t & 7) * 8;
    union { u16 s[8]; uint4 v; } pk;
    #pragma unroll
    for (int u = 0; u < 8; ++u) pk.s[u] = f2bf(tile[rb + u][c]);
    *(uint4*)&out[(size_t)(c0 + c) * R + r0 + rb] = pk.v;
  }
}

// ---------------- GEMM: C(MxN) = A(MxK,row) * BT(NxK,row)^T ----------------
// 128x128 tile, BK=32, 4 waves (2x2), 16x16x32 bf16 MFMA. M,N mult of 128, K mult of 32.
// MODE 0: bf16 store with scale; MODE 1: f32 store; MODE 2: f32 +=
template<int MODE>
__global__ __launch_bounds__(256) void gemm_bt(
    const u16* __restrict__ A, const u16* __restrict__ BT, void* __restrict__ C,
    int M, int N, int K, float scale)
{
  __shared__ u16 As[128 * 32];
  __shared__ u16 Bs[128 * 32];
  const int bm = blockIdx.y, bn = blockIdx.x;
  const int t = threadIdx.x;
  const int w = t >> 6, lane = t & 63;
  const int wr = w >> 1, wc = w & 1;
  const int lr = lane & 15, lkc = lane >> 4; // frag row / k-chunk

  f32x4 acc[4][4];
  const f32x4 z4 = { 0.f, 0.f, 0.f, 0.f };
  #pragma unroll
  for (int mi = 0; mi < 4; ++mi)
    #pragma unroll
    for (int ni = 0; ni < 4; ++ni) acc[mi][ni] = z4;

  // staging: chunk i (0..511): row=i>>2, dest chunk i&3 holds logical chunk swz4(row,i&3)
  const int i0 = t, i1 = t + 256;
  const int r0 = i0 >> 2, k0 = swz4(r0, i0 & 3) * 8;
  const int r1 = i1 >> 2, k1 = swz4(r1, i1 & 3) * 8;
  const u16* a0 = A + (size_t)(bm * 128 + r0) * K + k0;
  const u16* a1 = A + (size_t)(bm * 128 + r1) * K + k1;
  const u16* b0 = BT + (size_t)(bn * 128 + r0) * K + k0;
  const u16* b1 = BT + (size_t)(bn * 128 + r1) * K + k1;
  u16* As0 = As + (size_t)w * 512;        // wave-uniform LDS bases (HW adds lane*16B)
  u16* As1 = As + (size_t)(w + 4) * 512;
  u16* Bs0 = Bs + (size_t)w * 512;
  u16* Bs1 = Bs + (size_t)(w + 4) * 512;

  const int nk = K >> 5;
  for (int kt = 0; kt < nk; ++kt) {
    __syncthreads();
    GLDS16(a0, As0); GLDS16(a1, As1); GLDS16(b0, Bs0); GLDS16(b1, Bs1);
    a0 += 32; a1 += 32; b0 += 32; b1 += 32;
    __syncthreads();
    short8 af[4], bf[4];
    #pragma unroll
    for (int mi = 0; mi < 4; ++mi) {
      int row = wr * 64 + mi * 16 + lr;
      af[mi] = *(const short8*)&As[row * 32 + swz4(row, lkc) * 8];
    }
    #pragma unroll
    for (int ni = 0; ni < 4; ++ni) {
      int row = wc * 64 + ni * 16 + lr;
      bf[ni] = *(const short8*)&Bs[row * 32 + swz4(row, lkc) * 8];
    }
    #pragma unroll
    for (int mi = 0; mi < 4; ++mi)
      #pragma unroll
      for (int ni = 0; ni < 4; ++ni)
        acc[mi][ni] = __builtin_amdgcn_mfma_f32_16x16x32_bf16(af[mi], bf[ni], acc[mi][ni], 0, 0, 0);
  }

  const int row0 = bm * 128 + wr * 64, col0 = bn * 128 + wc * 64;
  const int rsub = (lane >> 4) * 4;
  #pragma unroll
  for (int mi = 0; mi < 4; ++mi) {
    #pragma unroll
    for (int ni = 0; ni < 4; ++ni) {
      #pragma unroll
      for (int r = 0; r < 4; ++r) {
        const size_t idx = (size_t)(row0 + mi * 16 + rsub + r) * N + (col0 + ni * 16 + lr);
        const float v = acc[mi][ni][r] * scale;
        if constexpr (MODE == 0)      ((u16*)C)[idx] = f2bf(v);
        else if constexpr (MODE == 1) ((float*)C)[idx] = v;
        else                          ((float*)C)[idx] += v;
      }
    }
  }
}

// ---------------- flash cross-attention v2 (multi-query: 1 KV head) ----------------
// Swapped-operand 32x32 structure:
//   QK^T computed as S^T = mfma(K, Q)  -> lane owns q = lane&31 (softmax lane-resident)
//   PV   computed as O^T = mfma(V^T, P) -> col = q = lane&31 (alpha/l rescale in-lane)
// Block: 4 waves; wave w -> head hb*4+w; each wave: 64 q-rows (2 q32 tiles).
// JBLK=128 KV rows staged per round (K via global_load_lds; V transposed via
// shfl-pair + packed b32 writes, bank-swizzled).
// grid (N/64, H/4, B), block 256
__global__ __launch_bounds__(256) void attn_kernel(
    const u16* __restrict__ q, const u16* __restrict__ kv, u16* __restrict__ o)
{
  __shared__ u16 Ks[128 * 64];      // [j][d], rows 128B = 8 chunks, slot ^= (j&7)
  __shared__ u16 Vt[64 * 128];      // [d][j], rows 256B, swz = (d&7)^((d>>3)&7) on 16B slots
  __shared__ u16 Ps[4][32 * 128];   // per-wave P [q][j], rows 256B, swz = (q&7); reused as f32 Ot
  const int b = blockIdx.z, hb = blockIdx.y, qb = blockIdx.x;
  const int t = threadIdx.x, w = t >> 6, lane = t & 63;
  const int q32 = lane & 31, hl = lane >> 5;
  const int hd = hb * 4 + w;

  const size_t qbase = (size_t)b * 2048 + qb * 64;
  short8 qa[2][4];
  #pragma unroll
  for (int t32 = 0; t32 < 2; ++t32)
    #pragma unroll
    for (int dq = 0; dq < 4; ++dq)
      qa[t32][dq] = *(const short8*)&q[(qbase + t32 * 32 + q32) * 1024 + hd * 64 + dq * 16 + hl * 8];

  f32x16 oacc[2][2];
  #pragma unroll
  for (int i = 0; i < 2; ++i)
    #pragma unroll
    for (int j = 0; j < 2; ++j)
      #pragma unroll
      for (int r = 0; r < 16; ++r) oacc[i][j][r] = 0.f;
  float m_[2] = { -1e30f, -1e30f }, l_[2] = { 0.f, 0.f };

  const size_t kvb = (size_t)b * 2048 * 128;
  const int vd0 = (t & 7) * 8;
  const int vodd = (t >> 3) & 1;
  u16* Pw = &Ps[w][0];

  for (int jt = 0; jt < 16; ++jt) {
    __syncthreads();
    // --- stage K: 128 rows x 64 d, 16B chunks, slot = logical ^ (row&7)
    #pragma unroll
    for (int n = 0; n < 4; ++n) {
      const int cc = n * 256 + w * 64;           // wave-uniform chunk base
      const int ccl = cc + lane;
      const int row = ccl >> 3, lc = (ccl & 7) ^ (row & 7);
      GLDS16(&kv[kvb + (size_t)(jt * 128 + row) * 128 + lc * 8], Ks + (size_t)cc * 8);
    }
    // --- stage V transposed: coalesced read + shfl pair-exchange + packed b32 writes
    #pragma unroll
    for (int c = 0; c < 4; ++c) {
      const int seg = c * 256 + t;
      const int vj = seg >> 3;
      const int jp = vj >> 1;
      const uint4 vv = *(const uint4*)&kv[kvb + (size_t)(jt * 128 + vj) * 128 + 64 + vd0];
      uint4 pvv;
      pvv.x = __shfl_xor((int)vv.x, 8);
      pvv.y = __shfl_xor((int)vv.y, 8);
      pvv.z = __shfl_xor((int)vv.z, 8);
      pvv.w = __shfl_xor((int)vv.w, 8);
      const unsigned ow[4] = { vv.x, vv.y, vv.z, vv.w };
      const unsigned pw[4] = { pvv.x, pvv.y, pvv.z, pvv.w };
      if (!vodd) {
        #pragma unroll
        for (int u = 0; u < 4; ++u) {
          const int d = vd0 + u;
          const unsigned own = (u & 1) ? (ow[u >> 1] >> 16) : (ow[u >> 1] & 0xffffu);
          const unsigned par = (u & 1) ? (pw[u >> 1] >> 16) : (pw[u >> 1] & 0xffffu);
          const int byteoff = d * 256 + ((4 * jp) ^ (((d & 7) ^ ((d >> 3) & 7)) << 4));
          *(unsigned*)((char*)Vt + byteoff) = own | (par << 16);
        }
      } else {
        #pragma unroll
        for (int u = 0; u < 4; ++u) {
          const int ue = u + 4;
          const int d = vd0 + ue;
          const unsigned own = (ue & 1) ? (ow[ue >> 1] >> 16) : (ow[ue >> 1] & 0xffffu);
          const unsigned par = (ue & 1) ? (pw[ue >> 1] >> 16) : (pw[ue >> 1] & 0xffffu);
          const int byteoff = d * 256 + ((4 * jp) ^ (((d & 7) ^ ((d >> 3) & 7)) << 4));
          *(unsigned*)((char*)Vt + byteoff) = par | (own << 16);
        }
      }
    }
    __syncthreads();

    #pragma unroll
    for (int t32 = 0; t32 < 2; ++t32) {
      // --- QK^T: S^T tiles, rows j (reg pattern), col q = lane&31
      f32x16 s[4];
      #pragma unroll
      for (int j32 = 0; j32 < 4; ++j32)
        #pragma unroll
        for (int r = 0; r < 16; ++r) s[j32][r] = 0.f;
      #pragma unroll
      for (int j32 = 0; j32 < 4; ++j32) {
        const int row = j32 * 32 + q32;
        #pragma unroll
        for (int dq = 0; dq < 4; ++dq) {
          const int slot = (dq * 2 + hl) ^ (row & 7);
          const short8 kf = *(const short8*)&Ks[row * 64 + slot * 8];
          s[j32] = __builtin_amdgcn_mfma_f32_32x32x16_bf16(kf, qa[t32][dq], s[j32], 0, 0, 0);
        }
      }
      // --- online softmax (all lane-resident for q = lane&31; j split across lane>>5)
      float mt = -1e30f;
      #pragma unroll
      for (int j32 = 0; j32 < 4; ++j32)
        #pragma unroll
        for (int r = 0; r < 16; ++r) mt = fmaxf(mt, s[j32][r]);
      mt = fmaxf(mt, __shfl_xor(mt, 32));
      const float nm = fmaxf(m_[t32], mt);
      const float alpha = __expf(m_[t32] - nm);
      m_[t32] = nm;
      float lsum = 0.f;
      #pragma unroll
      for (int j32 = 0; j32 < 4; ++j32) {
        float p[16];
        #pragma unroll
        for (int r = 0; r < 16; ++r) { p[r] = __expf(s[j32][r] - nm); lsum += p[r]; }
        #pragma unroll
        for (int g = 0; g < 4; ++g) {
          const unsigned lo = cvtpk(p[4 * g + 0], p[4 * g + 1]);
          const unsigned hi = cvtpk(p[4 * g + 2], p[4 * g + 3]);
          const int j2 = j32 * 64 + 16 * g + 8 * hl;             // 2 * j_base
          const int byteoff = q32 * 256 + (j2 ^ ((q32 & 7) << 4));
          uint2 wv; wv.x = lo; wv.y = hi;
          *(uint2*)((char*)Pw + byteoff) = wv;
        }
      }
      lsum += __shfl_xor(lsum, 32);
      l_[t32] = l_[t32] * alpha + lsum;
      #pragma unroll
      for (int d32 = 0; d32 < 2; ++d32)
        #pragma unroll
        for (int r = 0; r < 16; ++r) oacc[t32][d32][r] *= alpha;
      // --- PV: O^T = mfma(V^T, P); rows d (reg pattern), col q = lane&31
      short8 pf[8];
      #pragma unroll
      for (int kk = 0; kk < 8; ++kk) {
        const int byteoff = q32 * 256 + ((kk * 32 + hl * 16) ^ ((q32 & 7) << 4));
        pf[kk] = *(const short8*)((const char*)Pw + byteoff);
      }
      #pragma unroll
      for (int d32 = 0; d32 < 2; ++d32) {
        const int dr = d32 * 32 + q32;
        const int vswz = ((dr & 7) ^ ((dr >> 3) & 7)) << 4;
        #pragma unroll
        for (int kk = 0; kk < 8; ++kk) {
          const int byteoff = dr * 256 + ((kk * 32 + hl * 16) ^ vswz);
          const short8 vf = *(const short8*)((const char*)Vt + byteoff);
          oacc[t32][d32] = __builtin_amdgcn_mfma_f32_32x32x16_bf16(vf, pf[kk], oacc[t32][d32], 0, 0, 0);
        }
      }
    }
  }

  // --- epilogue: normalize (in-lane), transpose O^T -> O via wave-private LDS, store bf16
  float* Ot = (float*)Pw;
  #pragma unroll
  for (int t32 = 0; t32 < 2; ++t32) {
    const float inv = 1.0f / l_[t32];
    #pragma unroll
    for (int d32 = 0; d32 < 2; ++d32) {
      #pragma unroll
      for (int r = 0; r < 16; ++r) {
        const int d = (r & 3) + 8 * (r >> 2) + 4 * hl;
        const int byteoff = q32 * 128 + ((4 * d) ^ ((q32 & 7) << 4));
        *(float*)((char*)Ot + byteoff) = oacc[t32][d32][r] * inv;
      }
      const int qr = lane >> 1, dc = (lane & 1) * 16;
      union { u16 s[16]; uint4 v[2]; } ob;
      #pragma unroll
      for (int cch = 0; cch < 4; ++cch) {
        const int byteoff = qr * 128 + ((4 * (dc + 4 * cch)) ^ ((qr & 7) << 4));
        const f32x4 vv = *(const f32x4*)((const char*)Ot + byteoff);
        ob.s[cch * 4 + 0] = f2bf(vv[0]);
        ob.s[cch * 4 + 1] = f2bf(vv[1]);
        ob.s[cch * 4 + 2] = f2bf(vv[2]);
        ob.s[cch * 4 + 3] = f2bf(vv[3]);
      }
      u16* orow = &o[(qbase + t32 * 32 + qr) * 1024 + hd * 64 + d32 * 32 + dc];
      *(uint4*)orow = ob.v[0];
      *(uint4*)(orow + 8) = ob.v[1];
    }
  }
}

// ---------------- silu(gate)*a : ff (4096,8192) -> h (4096,4096) ----------------
__global__ __launch_bounds__(256) void silu_kernel(const u16* __restrict__ ff, u16* __restrict__ h)
{
  const size_t i = (size_t)blockIdx.x * 256 + threadIdx.x; // one 8-elem chunk
  const size_t row = i >> 9;
  const size_t c8 = (i & 511) * 8;
  const short8 av = *(const short8*)&ff[row * 8192 + c8];
  const short8 gv = *(const short8*)&ff[row * 8192 + 4096 + c8];
  union { u16 s[8]; uint4 v; } pk;
  #pragma unroll
  for (int u = 0; u < 8; ++u) {
    const float gg = bf2f((u16)gv[u]);
    const float aa = bf2f((u16)av[u]);
    const float sg = gg / (1.0f + __expf(-gg));
    pk.s[u] = f2bf(sg * aa);
  }
  *(uint4*)&h[row * 4096 + c8] = pk.v;
}

extern "C" void kernel_launch(void* const* d_in, const int* in_sizes, int n_in,
                              void* d_out, int out_size, void* d_ws, size_t ws_size,
                              hipStream_t stream)
{
  const float* x    = (const float*)d_in[0];
  const float* ctx  = (const float*)d_in[1];
  const float* ng   = (const float*)d_in[2];
  const float* nb   = (const float*)d_in[3];
  const float* cg   = (const float*)d_in[4];
  const float* cb   = (const float*)d_in[5];
  const float* Wq   = (const float*)d_in[6];
  const float* Wkv  = (const float*)d_in[7];
  const float* Wo   = (const float*)d_in[8];
  const float* Wff1 = (const float*)d_in[9];
  const float* Wff2 = (const float*)d_in[10];

  u16* p = (u16*)d_ws;
  u16* WqT   = p; p += (size_t)1024 * 1024;
  u16* WkvT  = p; p += (size_t)128 * 1024;
  u16* WoT   = p; p += (size_t)1024 * 1024;
  u16* Wff1T = p; p += (size_t)8192 * 1024;
  u16* Wff2T = p; p += (size_t)1024 * 4096;
  u16* xn    = p; p += (size_t)4096 * 1024;
  u16* cn    = p; p += (size_t)4096 * 1024;
  u16* qbuf  = p; p += (size_t)4096 * 1024;
  u16* kvbuf = p; p += (size_t)4096 * 128;
  u16* ao    = p; p += (size_t)4096 * 1024;
  u16* ffb   = p; p += (size_t)4096 * 8192;
  u16* hb    = p; p += (size_t)4096 * 4096;
  (void)in_sizes; (void)n_in; (void)out_size; (void)ws_size;

  ln_kernel<<<8192, 256, 0, stream>>>(x, ctx, ng, nb, cg, cb, xn, cn);

  transpose_k<<<dim3(16, 16), 256, 0, stream>>>(Wq,   WqT,   1024, 1024);
  transpose_k<<<dim3(2, 16),  256, 0, stream>>>(Wkv,  WkvT,  1024, 128);
  transpose_k<<<dim3(16, 16), 256, 0, stream>>>(Wo,   WoT,   1024, 1024);
  transpose_k<<<dim3(128, 16),256, 0, stream>>>(Wff1, Wff1T, 1024, 8192);
  transpose_k<<<dim3(16, 64), 256, 0, stream>>>(Wff2, Wff2T, 4096, 1024);

  // q = xn @ Wq * DH^-0.5   (4096x1024x1024)
  gemm_bt<0><<<dim3(8, 32), 256, 0, stream>>>(xn, WqT, qbuf, 4096, 1024, 1024, 0.125f);
  // kv = cn @ Wkv           (4096x128x1024)
  gemm_bt<0><<<dim3(1, 32), 256, 0, stream>>>(cn, WkvT, kvbuf, 4096, 128, 1024, 1.0f);
  // attention (swapped-operand 32x32 flash)
  attn_kernel<<<dim3(32, 4, 2), 256, 0, stream>>>(qbuf, kvbuf, ao);
  // out = ao @ Wo           (4096x1024x1024), f32 store
  gemm_bt<1><<<dim3(8, 32), 256, 0, stream>>>(ao, WoT, d_out, 4096, 1024, 1024, 1.0f);
  // ff = xn @ Wff1          (4096x8192x1024)
  gemm_bt<0><<<dim3(64, 32), 256, 0, stream>>>(xn, Wff1T, ffb, 4096, 8192, 1024, 1.0f);
  // h = silu(gate)*a
  silu_kernel<<<8192, 256, 0, stream>>>(ffb, hb);
  // out += h @ Wff2         (4096x1024x4096), f32 accumulate
  gemm_bt<2><<<dim3(8, 32), 256, 0, stream>>>(hb, Wff2T, d_out, 4096, 1024, 4096, 1.0f);
}

// Round 3
// 363.772 us; speedup vs baseline: 1.3053x; 1.1078x over previous
//
#include <hip/hip_runtime.h>
#include <stdint.h>

typedef unsigned short u16;
typedef __attribute__((ext_vector_type(8))) short short8;
typedef __attribute__((ext_vector_type(4))) float f32x4;
typedef __attribute__((ext_vector_type(16))) float f32x16;

#define GPTR(p) ((const __attribute__((address_space(1))) void*)(p))
#define SPTR(p) ((__attribute__((address_space(3))) void*)(p))
#define GLDS16(g, l) __builtin_amdgcn_global_load_lds(GPTR(g), SPTR(l), 16, 0, 0)

static __device__ __forceinline__ float bf2f(u16 u) {
  union { unsigned int i; float f; } c; c.i = ((unsigned int)u) << 16; return c.f;
}
static __device__ __forceinline__ u16 f2bf(float f) {
  union { float f; unsigned int u; } c; c.f = f;
  unsigned int r = 0x7fffu + ((c.u >> 16) & 1u);
  return (u16)((c.u + r) >> 16);
}
static __device__ __forceinline__ unsigned cvtpk(float a, float b) {
  unsigned r;
  asm volatile("v_cvt_pk_bf16_f32 %0, %1, %2" : "=v"(r) : "v"(a), "v"(b));
  return r;
}
// chunk swizzle for 64B rows (4x16B chunks): involution, spreads banks
static __device__ __forceinline__ int swz4(int row, int c) { return c ^ ((row >> 1) & 3); }

// ---------------- LayerNorm: f32 (rows of 1024) -> bf16 ----------------
__global__ __launch_bounds__(256) void ln_kernel(
    const float* __restrict__ x, const float* __restrict__ ctx,
    const float* __restrict__ g, const float* __restrict__ b,
    const float* __restrict__ cg, const float* __restrict__ cb,
    u16* __restrict__ xn, u16* __restrict__ cn)
{
  const int row = blockIdx.x;
  const float* src; const float* gg; const float* bb; u16* dst;
  if (row < 4096) { src = x + (size_t)row * 1024; gg = g;  bb = b;  dst = xn + (size_t)row * 1024; }
  else            { src = ctx + (size_t)(row - 4096) * 1024; gg = cg; bb = cb; dst = cn + (size_t)(row - 4096) * 1024; }
  const int t = threadIdx.x;
  float4 v = *(const float4*)&src[t * 4];
  float s  = v.x + v.y + v.z + v.w;
  float s2 = v.x * v.x + v.y * v.y + v.z * v.z + v.w * v.w;
  #pragma unroll
  for (int off = 1; off < 64; off <<= 1) { s += __shfl_xor(s, off); s2 += __shfl_xor(s2, off); }
  __shared__ float ls[4], ls2[4];
  const int w = t >> 6;
  if ((t & 63) == 0) { ls[w] = s; ls2[w] = s2; }
  __syncthreads();
  s  = ls[0] + ls[1] + ls[2] + ls[3];
  s2 = ls2[0] + ls2[1] + ls2[2] + ls2[3];
  const float mu   = s * (1.0f / 1024.0f);
  const float var  = s2 * (1.0f / 1024.0f) - mu * mu;
  const float rstd = rsqrtf(var + 1e-5f);
  float xv[4] = { v.x, v.y, v.z, v.w };
  u16 o[4];
  #pragma unroll
  for (int i = 0; i < 4; ++i)
    o[i] = f2bf((xv[i] - mu) * rstd * gg[t * 4 + i] + bb[t * 4 + i]);
  uint2 pv;
  pv.x = (unsigned)o[0] | ((unsigned)o[1] << 16);
  pv.y = (unsigned)o[2] | ((unsigned)o[3] << 16);
  *(uint2*)&dst[t * 4] = pv;
}

// ---------------- transpose+convert: f32 (R,C) -> bf16 (C,R), optional scale ----------------
// grid: (C/64, R/64), block 256
__global__ __launch_bounds__(256) void transpose_k(
    const float* __restrict__ in, u16* __restrict__ out, int R, int C, float scale)
{
  __shared__ float tile[64][65];
  const int c0 = blockIdx.x * 64, r0 = blockIdx.y * 64;
  const int t = threadIdx.x;
  const int tr = t >> 4, tc = (t & 15) * 4;
  #pragma unroll
  for (int i = 0; i < 4; ++i) {
    int r = tr + i * 16;
    float4 v = *(const float4*)&in[(size_t)(r0 + r) * C + c0 + tc];
    tile[r][tc + 0] = v.x; tile[r][tc + 1] = v.y; tile[r][tc + 2] = v.z; tile[r][tc + 3] = v.w;
  }
  __syncthreads();
  #pragma unroll
  for (int i = 0; i < 2; ++i) {
    int c  = (t >> 3) + i * 32;
    int rb = (t & 7) * 8;
    union { u16 s[8]; uint4 v; } pk;
    #pragma unroll
    for (int u = 0; u < 8; ++u) pk.s[u] = f2bf(tile[rb + u][c] * scale);
    *(uint4*)&out[(size_t)(c0 + c) * R + r0 + rb] = pk.v;
  }
}

// ---------------- GEMM: C(MxN) = A(MxK,row) * BT(NxK,row)^T ----------------
// 128x128 tile, BK=32, 4 waves (2x2), 16x16x32 bf16 MFMA. M,N mult of 128, K mult of 32.
// MODE 0: bf16 store with scale; MODE 1: f32 store; MODE 2: f32 +=
template<int MODE>
__global__ __launch_bounds__(256) void gemm_bt(
    const u16* __restrict__ A, const u16* __restrict__ BT, void* __restrict__ C,
    int M, int N, int K, float scale)
{
  __shared__ u16 As[128 * 32];
  __shared__ u16 Bs[128 * 32];
  const int bm = blockIdx.y, bn = blockIdx.x;
  const int t = threadIdx.x;
  const int w = t >> 6, lane = t & 63;
  const int wr = w >> 1, wc = w & 1;
  const int lr = lane & 15, lkc = lane >> 4; // frag row / k-chunk

  f32x4 acc[4][4];
  const f32x4 z4 = { 0.f, 0.f, 0.f, 0.f };
  #pragma unroll
  for (int mi = 0; mi < 4; ++mi)
    #pragma unroll
    for (int ni = 0; ni < 4; ++ni) acc[mi][ni] = z4;

  const int i0 = t, i1 = t + 256;
  const int r0 = i0 >> 2, k0 = swz4(r0, i0 & 3) * 8;
  const int r1 = i1 >> 2, k1 = swz4(r1, i1 & 3) * 8;
  const u16* a0 = A + (size_t)(bm * 128 + r0) * K + k0;
  const u16* a1 = A + (size_t)(bm * 128 + r1) * K + k1;
  const u16* b0 = BT + (size_t)(bn * 128 + r0) * K + k0;
  const u16* b1 = BT + (size_t)(bn * 128 + r1) * K + k1;
  u16* As0 = As + (size_t)w * 512;
  u16* As1 = As + (size_t)(w + 4) * 512;
  u16* Bs0 = Bs + (size_t)w * 512;
  u16* Bs1 = Bs + (size_t)(w + 4) * 512;

  const int nk = K >> 5;
  for (int kt = 0; kt < nk; ++kt) {
    __syncthreads();
    GLDS16(a0, As0); GLDS16(a1, As1); GLDS16(b0, Bs0); GLDS16(b1, Bs1);
    a0 += 32; a1 += 32; b0 += 32; b1 += 32;
    __syncthreads();
    short8 af[4], bf[4];
    #pragma unroll
    for (int mi = 0; mi < 4; ++mi) {
      int row = wr * 64 + mi * 16 + lr;
      af[mi] = *(const short8*)&As[row * 32 + swz4(row, lkc) * 8];
    }
    #pragma unroll
    for (int ni = 0; ni < 4; ++ni) {
      int row = wc * 64 + ni * 16 + lr;
      bf[ni] = *(const short8*)&Bs[row * 32 + swz4(row, lkc) * 8];
    }
    #pragma unroll
    for (int mi = 0; mi < 4; ++mi)
      #pragma unroll
      for (int ni = 0; ni < 4; ++ni)
        acc[mi][ni] = __builtin_amdgcn_mfma_f32_16x16x32_bf16(af[mi], bf[ni], acc[mi][ni], 0, 0, 0);
  }

  const int row0 = bm * 128 + wr * 64, col0 = bn * 128 + wc * 64;
  const int rsub = (lane >> 4) * 4;
  #pragma unroll
  for (int mi = 0; mi < 4; ++mi) {
    #pragma unroll
    for (int ni = 0; ni < 4; ++ni) {
      #pragma unroll
      for (int r = 0; r < 4; ++r) {
        const size_t idx = (size_t)(row0 + mi * 16 + rsub + r) * N + (col0 + ni * 16 + lr);
        const float v = acc[mi][ni][r] * scale;
        if constexpr (MODE == 0)      ((u16*)C)[idx] = f2bf(v);
        else if constexpr (MODE == 1) ((float*)C)[idx] = v;
        else                          ((float*)C)[idx] += v;
      }
    }
  }
}

// ---------------- split-K GEMM: partial[z] (f32, MxN) = A[:, zKs:(z+1)Ks] * BT^T ----------------
// grid (N/128, M/128, S)
__global__ __launch_bounds__(256) void gemm_bt_sk(
    const u16* __restrict__ A, const u16* __restrict__ BT, float* __restrict__ Cp,
    int M, int N, int Kslice, int Ktot)
{
  __shared__ u16 As[128 * 32];
  __shared__ u16 Bs[128 * 32];
  const int bm = blockIdx.y, bn = blockIdx.x, z = blockIdx.z;
  const int t = threadIdx.x;
  const int w = t >> 6, lane = t & 63;
  const int wr = w >> 1, wc = w & 1;
  const int lr = lane & 15, lkc = lane >> 4;

  f32x4 acc[4][4];
  const f32x4 z4 = { 0.f, 0.f, 0.f, 0.f };
  #pragma unroll
  for (int mi = 0; mi < 4; ++mi)
    #pragma unroll
    for (int ni = 0; ni < 4; ++ni) acc[mi][ni] = z4;

  const int kbase = z * Kslice;
  const int i0 = t, i1 = t + 256;
  const int r0 = i0 >> 2, k0 = swz4(r0, i0 & 3) * 8;
  const int r1 = i1 >> 2, k1 = swz4(r1, i1 & 3) * 8;
  const u16* a0 = A + (size_t)(bm * 128 + r0) * Ktot + kbase + k0;
  const u16* a1 = A + (size_t)(bm * 128 + r1) * Ktot + kbase + k1;
  const u16* b0 = BT + (size_t)(bn * 128 + r0) * Ktot + kbase + k0;
  const u16* b1 = BT + (size_t)(bn * 128 + r1) * Ktot + kbase + k1;
  u16* As0 = As + (size_t)w * 512;
  u16* As1 = As + (size_t)(w + 4) * 512;
  u16* Bs0 = Bs + (size_t)w * 512;
  u16* Bs1 = Bs + (size_t)(w + 4) * 512;

  const int nk = Kslice >> 5;
  for (int kt = 0; kt < nk; ++kt) {
    __syncthreads();
    GLDS16(a0, As0); GLDS16(a1, As1); GLDS16(b0, Bs0); GLDS16(b1, Bs1);
    a0 += 32; a1 += 32; b0 += 32; b1 += 32;
    __syncthreads();
    short8 af[4], bf[4];
    #pragma unroll
    for (int mi = 0; mi < 4; ++mi) {
      int row = wr * 64 + mi * 16 + lr;
      af[mi] = *(const short8*)&As[row * 32 + swz4(row, lkc) * 8];
    }
    #pragma unroll
    for (int ni = 0; ni < 4; ++ni) {
      int row = wc * 64 + ni * 16 + lr;
      bf[ni] = *(const short8*)&Bs[row * 32 + swz4(row, lkc) * 8];
    }
    #pragma unroll
    for (int mi = 0; mi < 4; ++mi)
      #pragma unroll
      for (int ni = 0; ni < 4; ++ni)
        acc[mi][ni] = __builtin_amdgcn_mfma_f32_16x16x32_bf16(af[mi], bf[ni], acc[mi][ni], 0, 0, 0);
  }

  float* C = Cp + (size_t)z * M * N;
  const int row0 = bm * 128 + wr * 64, col0 = bn * 128 + wc * 64;
  const int rsub = (lane >> 4) * 4;
  #pragma unroll
  for (int mi = 0; mi < 4; ++mi)
    #pragma unroll
    for (int ni = 0; ni < 4; ++ni)
      #pragma unroll
      for (int r = 0; r < 4; ++r)
        C[(size_t)(row0 + mi * 16 + rsub + r) * N + (col0 + ni * 16 + lr)] = acc[mi][ni][r];
}

// ---------------- reduce 8 f32 partials (4096x128) -> bf16 ----------------
__global__ __launch_bounds__(256) void reduce_kv(const float* __restrict__ part, u16* __restrict__ out)
{
  const size_t base = ((size_t)blockIdx.x * 256 + threadIdx.x) * 4;
  f32x4 s = *(const f32x4*)&part[base];
  #pragma unroll
  for (int zz = 1; zz < 8; ++zz) {
    const f32x4 v = *(const f32x4*)&part[(size_t)zz * 524288 + base];
    s[0] += v[0]; s[1] += v[1]; s[2] += v[2]; s[3] += v[3];
  }
  uint2 pv;
  pv.x = (unsigned)f2bf(s[0]) | ((unsigned)f2bf(s[1]) << 16);
  pv.y = (unsigned)f2bf(s[2]) | ((unsigned)f2bf(s[3]) << 16);
  *(uint2*)&out[base] = pv;
}

// ---------------- d_out += sum of 4 f32 partials (4096x1024) ----------------
__global__ __launch_bounds__(256) void reduce_acc(const float* __restrict__ part, float* __restrict__ out)
{
  const size_t base = ((size_t)blockIdx.x * 256 + threadIdx.x) * 4;
  f32x4 s = *(const f32x4*)&out[base];
  #pragma unroll
  for (int zz = 0; zz < 4; ++zz) {
    const f32x4 v = *(const f32x4*)&part[(size_t)zz * 4194304 + base];
    s[0] += v[0]; s[1] += v[1]; s[2] += v[2]; s[3] += v[3];
  }
  *(f32x4*)&out[base] = s;
}

// ---------------- flash cross-attention (multi-query: 1 KV head) ----------------
// q cols 0..1023 of the fused qff buffer (row stride 9216), pre-scaled via W1T
// kv: (B*J, 128) bf16: K at [0..63], V at [64..127];  o: (B*N, 1024) bf16
// grid (N/64, H/4, B), block 256; wave w -> head hb*4+w; 64 q-rows per wave
__global__ __launch_bounds__(256) void attn_kernel(
    const u16* __restrict__ q, const u16* __restrict__ kv, u16* __restrict__ o)
{
  __shared__ u16 Ks[128 * 64];      // [j][d], rows 128B = 8 chunks, slot ^= (j&7)
  __shared__ u16 Vt[64 * 128];      // [d][j], rows 256B, swz = (d&7)^((d>>3)&7) on 16B slots
  __shared__ u16 Ps[4][32 * 128];   // per-wave P [q][j], rows 256B, swz = (q&7); reused as f32 Ot
  const int b = blockIdx.z, hb = blockIdx.y, qb = blockIdx.x;
  const int t = threadIdx.x, w = t >> 6, lane = t & 63;
  const int q32 = lane & 31, hl = lane >> 5;
  const int hd = hb * 4 + w;

  const size_t qbase = (size_t)b * 2048 + qb * 64;
  short8 qa[2][4];
  #pragma unroll
  for (int t32 = 0; t32 < 2; ++t32)
    #pragma unroll
    for (int dq = 0; dq < 4; ++dq)
      qa[t32][dq] = *(const short8*)&q[(qbase + t32 * 32 + q32) * 9216 + hd * 64 + dq * 16 + hl * 8];

  f32x16 oacc[2][2];
  #pragma unroll
  for (int i = 0; i < 2; ++i)
    #pragma unroll
    for (int j = 0; j < 2; ++j)
      #pragma unroll
      for (int r = 0; r < 16; ++r) oacc[i][j][r] = 0.f;
  float m_[2] = { -1e30f, -1e30f }, l_[2] = { 0.f, 0.f };

  const size_t kvb = (size_t)b * 2048 * 128;
  const int vd0 = (t & 7) * 8;
  const int vodd = (t >> 3) & 1;
  u16* Pw = &Ps[w][0];

  for (int jt = 0; jt < 16; ++jt) {
    __syncthreads();
    #pragma unroll
    for (int n = 0; n < 4; ++n) {
      const int cc = n * 256 + w * 64;
      const int ccl = cc + lane;
      const int row = ccl >> 3, lc = (ccl & 7) ^ (row & 7);
      GLDS16(&kv[kvb + (size_t)(jt * 128 + row) * 128 + lc * 8], Ks + (size_t)cc * 8);
    }
    #pragma unroll
    for (int c = 0; c < 4; ++c) {
      const int seg = c * 256 + t;
      const int vj = seg >> 3;
      const int jp = vj >> 1;
      const uint4 vv = *(const uint4*)&kv[kvb + (size_t)(jt * 128 + vj) * 128 + 64 + vd0];
      uint4 pvv;
      pvv.x = __shfl_xor((int)vv.x, 8);
      pvv.y = __shfl_xor((int)vv.y, 8);
      pvv.z = __shfl_xor((int)vv.z, 8);
      pvv.w = __shfl_xor((int)vv.w, 8);
      const unsigned ow[4] = { vv.x, vv.y, vv.z, vv.w };
      const unsigned pw[4] = { pvv.x, pvv.y, pvv.z, pvv.w };
      if (!vodd) {
        #pragma unroll
        for (int u = 0; u < 4; ++u) {
          const int d = vd0 + u;
          const unsigned own = (u & 1) ? (ow[u >> 1] >> 16) : (ow[u >> 1] & 0xffffu);
          const unsigned par = (u & 1) ? (pw[u >> 1] >> 16) : (pw[u >> 1] & 0xffffu);
          const int byteoff = d * 256 + ((4 * jp) ^ (((d & 7) ^ ((d >> 3) & 7)) << 4));
          *(unsigned*)((char*)Vt + byteoff) = own | (par << 16);
        }
      } else {
        #pragma unroll
        for (int u = 0; u < 4; ++u) {
          const int ue = u + 4;
          const int d = vd0 + ue;
          const unsigned own = (ue & 1) ? (ow[ue >> 1] >> 16) : (ow[ue >> 1] & 0xffffu);
          const unsigned par = (ue & 1) ? (pw[ue >> 1] >> 16) : (pw[ue >> 1] & 0xffffu);
          const int byteoff = d * 256 + ((4 * jp) ^ (((d & 7) ^ ((d >> 3) & 7)) << 4));
          *(unsigned*)((char*)Vt + byteoff) = par | (own << 16);
        }
      }
    }
    __syncthreads();

    #pragma unroll
    for (int t32 = 0; t32 < 2; ++t32) {
      f32x16 s[4];
      #pragma unroll
      for (int j32 = 0; j32 < 4; ++j32)
        #pragma unroll
        for (int r = 0; r < 16; ++r) s[j32][r] = 0.f;
      #pragma unroll
      for (int j32 = 0; j32 < 4; ++j32) {
        const int row = j32 * 32 + q32;
        #pragma unroll
        for (int dq = 0; dq < 4; ++dq) {
          const int slot = (dq * 2 + hl) ^ (row & 7);
          const short8 kf = *(const short8*)&Ks[row * 64 + slot * 8];
          s[j32] = __builtin_amdgcn_mfma_f32_32x32x16_bf16(kf, qa[t32][dq], s[j32], 0, 0, 0);
        }
      }
      float mt = -1e30f;
      #pragma unroll
      for (int j32 = 0; j32 < 4; ++j32)
        #pragma unroll
        for (int r = 0; r < 16; ++r) mt = fmaxf(mt, s[j32][r]);
      mt = fmaxf(mt, __shfl_xor(mt, 32));
      const float nm = fmaxf(m_[t32], mt);
      const float alpha = __expf(m_[t32] - nm);
      m_[t32] = nm;
      float lsum = 0.f;
      #pragma unroll
      for (int j32 = 0; j32 < 4; ++j32) {
        float p[16];
        #pragma unroll
        for (int r = 0; r < 16; ++r) { p[r] = __expf(s[j32][r] - nm); lsum += p[r]; }
        #pragma unroll
        for (int g = 0; g < 4; ++g) {
          const unsigned lo = cvtpk(p[4 * g + 0], p[4 * g + 1]);
          const unsigned hi = cvtpk(p[4 * g + 2], p[4 * g + 3]);
          const int j2 = j32 * 64 + 16 * g + 8 * hl;
          const int byteoff = q32 * 256 + (j2 ^ ((q32 & 7) << 4));
          uint2 wv; wv.x = lo; wv.y = hi;
          *(uint2*)((char*)Pw + byteoff) = wv;
        }
      }
      lsum += __shfl_xor(lsum, 32);
      l_[t32] = l_[t32] * alpha + lsum;
      #pragma unroll
      for (int d32 = 0; d32 < 2; ++d32)
        #pragma unroll
        for (int r = 0; r < 16; ++r) oacc[t32][d32][r] *= alpha;
      short8 pf[8];
      #pragma unroll
      for (int kk = 0; kk < 8; ++kk) {
        const int byteoff = q32 * 256 + ((kk * 32 + hl * 16) ^ ((q32 & 7) << 4));
        pf[kk] = *(const short8*)((const char*)Pw + byteoff);
      }
      #pragma unroll
      for (int d32 = 0; d32 < 2; ++d32) {
        const int dr = d32 * 32 + q32;
        const int vswz = ((dr & 7) ^ ((dr >> 3) & 7)) << 4;
        #pragma unroll
        for (int kk = 0; kk < 8; ++kk) {
          const int byteoff = dr * 256 + ((kk * 32 + hl * 16) ^ vswz);
          const short8 vf = *(const short8*)((const char*)Vt + byteoff);
          oacc[t32][d32] = __builtin_amdgcn_mfma_f32_32x32x16_bf16(vf, pf[kk], oacc[t32][d32], 0, 0, 0);
        }
      }
    }
  }

  float* Ot = (float*)Pw;
  #pragma unroll
  for (int t32 = 0; t32 < 2; ++t32) {
    const float inv = 1.0f / l_[t32];
    #pragma unroll
    for (int d32 = 0; d32 < 2; ++d32) {
      #pragma unroll
      for (int r = 0; r < 16; ++r) {
        const int d = (r & 3) + 8 * (r >> 2) + 4 * hl;
        const int byteoff = q32 * 128 + ((4 * d) ^ ((q32 & 7) << 4));
        *(float*)((char*)Ot + byteoff) = oacc[t32][d32][r] * inv;
      }
      const int qr = lane >> 1, dc = (lane & 1) * 16;
      union { u16 s[16]; uint4 v[2]; } ob;
      #pragma unroll
      for (int cch = 0; cch < 4; ++cch) {
        const int byteoff = qr * 128 + ((4 * (dc + 4 * cch)) ^ ((qr & 7) << 4));
        const f32x4 vv = *(const f32x4*)((const char*)Ot + byteoff);
        ob.s[cch * 4 + 0] = f2bf(vv[0]);
        ob.s[cch * 4 + 1] = f2bf(vv[1]);
        ob.s[cch * 4 + 2] = f2bf(vv[2]);
        ob.s[cch * 4 + 3] = f2bf(vv[3]);
      }
      u16* orow = &o[(qbase + t32 * 32 + qr) * 1024 + hd * 64 + d32 * 32 + dc];
      *(uint4*)orow = ob.v[0];
      *(uint4*)(orow + 8) = ob.v[1];
    }
  }
}

// ---------------- silu(gate)*a from fused qff (a@1024, gate@5120) -> h (4096,4096) ----------------
__global__ __launch_bounds__(256) void silu_kernel(const u16* __restrict__ qff, u16* __restrict__ h)
{
  const size_t i = (size_t)blockIdx.x * 256 + threadIdx.x;
  const size_t row = i >> 9;
  const size_t c8 = (i & 511) * 8;
  const short8 av = *(const short8*)&qff[row * 9216 + 1024 + c8];
  const short8 gv = *(const short8*)&qff[row * 9216 + 5120 + c8];
  union { u16 s[8]; uint4 v; } pk;
  #pragma unroll
  for (int u = 0; u < 8; ++u) {
    const float gg = bf2f((u16)gv[u]);
    const float aa = bf2f((u16)av[u]);
    const float sg = gg / (1.0f + __expf(-gg));
    pk.s[u] = f2bf(sg * aa);
  }
  *(uint4*)&h[row * 4096 + c8] = pk.v;
}

extern "C" void kernel_launch(void* const* d_in, const int* in_sizes, int n_in,
                              void* d_out, int out_size, void* d_ws, size_t ws_size,
                              hipStream_t stream)
{
  const float* x    = (const float*)d_in[0];
  const float* ctx  = (const float*)d_in[1];
  const float* ng   = (const float*)d_in[2];
  const float* nb   = (const float*)d_in[3];
  const float* cg   = (const float*)d_in[4];
  const float* cb   = (const float*)d_in[5];
  const float* Wq   = (const float*)d_in[6];
  const float* Wkv  = (const float*)d_in[7];
  const float* Wo   = (const float*)d_in[8];
  const float* Wff1 = (const float*)d_in[9];
  const float* Wff2 = (const float*)d_in[10];

  u16* p = (u16*)d_ws;
  u16* W1T   = p; p += (size_t)9216 * 1024;   // [Wq*0.125 | Wff1]^T, 18 MB
  u16* WkvT  = p; p += (size_t)128 * 1024;
  u16* WoT   = p; p += (size_t)1024 * 1024;
  u16* Wff2T = p; p += (size_t)1024 * 4096;
  u16* xn    = p; p += (size_t)4096 * 1024;
  u16* cn    = p; p += (size_t)4096 * 1024;
  u16* qff   = p; p += (size_t)4096 * 9216;   // 72 MB: q | a | gate
  u16* kvbuf = p; p += (size_t)4096 * 128;
  u16* ao    = p; p += (size_t)4096 * 1024;
  u16* hb    = p; p += (size_t)4096 * 4096;   // 32 MB
  float* kvpart = (float*)hb;                  // 8 x (4096x128) f32 = 16 MB, dead before silu
  float* ffpart = (float*)qff;                 // 4 x (4096x1024) f32 = 64 MB, dead after attn
  (void)in_sizes; (void)n_in; (void)out_size; (void)ws_size;

  ln_kernel<<<8192, 256, 0, stream>>>(x, ctx, ng, nb, cg, cb, xn, cn);

  transpose_k<<<dim3(16, 16),  256, 0, stream>>>(Wq,   W1T,                       1024, 1024, 0.125f);
  transpose_k<<<dim3(128, 16), 256, 0, stream>>>(Wff1, W1T + (size_t)1024 * 1024, 1024, 8192, 1.0f);
  transpose_k<<<dim3(2, 16),   256, 0, stream>>>(Wkv,  WkvT,  1024, 128,  1.0f);
  transpose_k<<<dim3(16, 16),  256, 0, stream>>>(Wo,   WoT,   1024, 1024, 1.0f);
  transpose_k<<<dim3(16, 64),  256, 0, stream>>>(Wff2, Wff2T, 4096, 1024, 1.0f);

  // qff = xn @ [Wq*scale | Wff1]   (4096 x 9216 x 1024), 2304 blocks
  gemm_bt<0><<<dim3(72, 32), 256, 0, stream>>>(xn, W1T, qff, 4096, 9216, 1024, 1.0f);
  // kv = cn @ Wkv, split-K 8 -> partials in hb region, then reduce to bf16
  gemm_bt_sk<<<dim3(1, 32, 8), 256, 0, stream>>>(cn, WkvT, kvpart, 4096, 128, 128, 1024);
  reduce_kv<<<512, 256, 0, stream>>>(kvpart, kvbuf);
  // h = silu(gate)*a (clobbers kvpart region)
  silu_kernel<<<8192, 256, 0, stream>>>(qff, hb);
  // attention (reads q part of qff + kvbuf)
  attn_kernel<<<dim3(32, 4, 2), 256, 0, stream>>>(qff, kvbuf, ao);
  // out = ao @ Wo (f32 store)
  gemm_bt<1><<<dim3(8, 32), 256, 0, stream>>>(ao, WoT, d_out, 4096, 1024, 1024, 1.0f);
  // out += h @ Wff2, split-K 4 -> partials in qff region (dead now), then reduce-acc
  gemm_bt_sk<<<dim3(8, 32, 4), 256, 0, stream>>>(hb, Wff2T, ffpart, 4096, 1024, 1024, 4096);
  reduce_acc<<<4096, 256, 0, stream>>>(ffpart, (float*)d_out);
}

// Round 4
// 316.242 us; speedup vs baseline: 1.5015x; 1.1503x over previous
//
#include <hip/hip_runtime.h>
#include <stdint.h>

typedef unsigned short u16;
typedef __attribute__((ext_vector_type(8))) short short8;
typedef __attribute__((ext_vector_type(4))) float f32x4;
typedef __attribute__((ext_vector_type(16))) float f32x16;

#define GPTR(p) ((const __attribute__((address_space(1))) void*)(p))
#define SPTR(p) ((__attribute__((address_space(3))) void*)(p))
#define GLDS16(g, l) __builtin_amdgcn_global_load_lds(GPTR(g), SPTR(l), 16, 0, 0)

static __device__ __forceinline__ float bf2f(u16 u) {
  union { unsigned int i; float f; } c; c.i = ((unsigned int)u) << 16; return c.f;
}
static __device__ __forceinline__ u16 f2bf(float f) {
  union { float f; unsigned int u; } c; c.f = f;
  unsigned int r = 0x7fffu + ((c.u >> 16) & 1u);
  return (u16)((c.u + r) >> 16);
}
static __device__ __forceinline__ unsigned cvtpk(float a, float b) {
  unsigned r;
  asm volatile("v_cvt_pk_bf16_f32 %0, %1, %2" : "=v"(r) : "v"(a), "v"(b));
  return r;
}
static __device__ __forceinline__ int swz4(int row, int c) { return c ^ ((row >> 1) & 3); }

// ---------------- LayerNorm: f32 (rows of 1024) -> bf16 ----------------
__global__ __launch_bounds__(256) void ln_kernel(
    const float* __restrict__ x, const float* __restrict__ ctx,
    const float* __restrict__ g, const float* __restrict__ b,
    const float* __restrict__ cg, const float* __restrict__ cb,
    u16* __restrict__ xn, u16* __restrict__ cn)
{
  const int row = blockIdx.x;
  const float* src; const float* gg; const float* bb; u16* dst;
  if (row < 4096) { src = x + (size_t)row * 1024; gg = g;  bb = b;  dst = xn + (size_t)row * 1024; }
  else            { src = ctx + (size_t)(row - 4096) * 1024; gg = cg; bb = cb; dst = cn + (size_t)(row - 4096) * 1024; }
  const int t = threadIdx.x;
  float4 v = *(const float4*)&src[t * 4];
  float s  = v.x + v.y + v.z + v.w;
  float s2 = v.x * v.x + v.y * v.y + v.z * v.z + v.w * v.w;
  #pragma unroll
  for (int off = 1; off < 64; off <<= 1) { s += __shfl_xor(s, off); s2 += __shfl_xor(s2, off); }
  __shared__ float ls[4], ls2[4];
  const int w = t >> 6;
  if ((t & 63) == 0) { ls[w] = s; ls2[w] = s2; }
  __syncthreads();
  s  = ls[0] + ls[1] + ls[2] + ls[3];
  s2 = ls2[0] + ls2[1] + ls2[2] + ls2[3];
  const float mu   = s * (1.0f / 1024.0f);
  const float var  = s2 * (1.0f / 1024.0f) - mu * mu;
  const float rstd = rsqrtf(var + 1e-5f);
  float xv[4] = { v.x, v.y, v.z, v.w };
  u16 o[4];
  #pragma unroll
  for (int i = 0; i < 4; ++i)
    o[i] = f2bf((xv[i] - mu) * rstd * gg[t * 4 + i] + bb[t * 4 + i]);
  uint2 pv;
  pv.x = (unsigned)o[0] | ((unsigned)o[1] << 16);
  pv.y = (unsigned)o[2] | ((unsigned)o[3] << 16);
  *(uint2*)&dst[t * 4] = pv;
}

// ---------------- transpose+convert: f32 (R,C) -> bf16 (C,R) with out leading dim ----------------
__global__ __launch_bounds__(256) void transpose_k(
    const float* __restrict__ in, u16* __restrict__ out, int R, int C, int ldo, float scale)
{
  __shared__ float tile[64][65];
  const int c0 = blockIdx.x * 64, r0 = blockIdx.y * 64;
  const int t = threadIdx.x;
  const int tr = t >> 4, tc = (t & 15) * 4;
  #pragma unroll
  for (int i = 0; i < 4; ++i) {
    int r = tr + i * 16;
    float4 v = *(const float4*)&in[(size_t)(r0 + r) * C + c0 + tc];
    tile[r][tc + 0] = v.x; tile[r][tc + 1] = v.y; tile[r][tc + 2] = v.z; tile[r][tc + 3] = v.w;
  }
  __syncthreads();
  #pragma unroll
  for (int i = 0; i < 2; ++i) {
    int c  = (t >> 3) + i * 32;
    int rb = (t & 7) * 8;
    union { u16 s[8]; uint4 v; } pk;
    #pragma unroll
    for (int u = 0; u < 8; ++u) pk.s[u] = f2bf(tile[rb + u][c] * scale);
    *(uint4*)&out[(size_t)(c0 + c) * ldo + r0 + rb] = pk.v;
  }
}

// =============== 8-phase 256x256 GEMM (BK=64, 8 waves, 2-deep dbuf) ===============
// C(M,N) = A(M,Ktot)[:, kb:kb+Kslice] * BT(N,Ktot)[:, kb:kb+Kslice]^T, kb = blockIdx.y*Kslice
// MODE 0: bf16 store to C; MODE 1: f32 store to C + z*M*N (split-K partials)
// LDS: per buf, A[256][64] and B[256][64] bf16, chunk-swizzled: phys chunk = logical ^ (row&7).
// Stage halves: A-half h = rows {h*64..h*64+63} U {128+h*64..191+h*64}; B-half h = rows h*128..h*128+127.
// Steady-state stage slots (tileX = 2i+2 -> buf0, tileY = 2i+3 -> buf1):
//   P0: buf1.A1(2i+1)  P1: buf0.B0(X)  P2: buf0.B1(X)  P3: buf0.A0(X) + gate vmcnt(6)
//   P4: buf0.A1(X)     P5: buf1.B0(Y)  P6: buf1.B1(Y)  P7: buf1.A0(Y) + gate vmcnt(6)
// Gate math: needed 4 halves (8 wave-loads) are always exactly 6 loads older than newest -> vmcnt(6).
#define MM1(MQ, M, NN, BF) acc[MQ][M][NN] = __builtin_amdgcn_mfma_f32_16x16x32_bf16(af##M, BF, acc[MQ][M][NN], 0, 0, 0)
#define MFMA16(MQ, KS) \
  MM1(MQ,0,0,bf##KS##0); MM1(MQ,0,1,bf##KS##1); MM1(MQ,0,2,bf##KS##2); MM1(MQ,0,3,bf##KS##3); \
  MM1(MQ,1,0,bf##KS##0); MM1(MQ,1,1,bf##KS##1); MM1(MQ,1,2,bf##KS##2); MM1(MQ,1,3,bf##KS##3); \
  MM1(MQ,2,0,bf##KS##0); MM1(MQ,2,1,bf##KS##1); MM1(MQ,2,2,bf##KS##2); MM1(MQ,2,3,bf##KS##3); \
  MM1(MQ,3,0,bf##KS##0); MM1(MQ,3,1,bf##KS##1); MM1(MQ,3,2,bf##KS##2); MM1(MQ,3,3,bf##KS##3)

#define SG_A(SBUF, H, KT) do { \
    GLDS16(gA[H][0] + ((size_t)(KT) << 6), SBUF + ((H) * 64 + w16o) * 64); \
    GLDS16(gA[H][1] + ((size_t)(KT) << 6), SBUF + ((H) * 64 + w16o + 8) * 64); \
  } while (0)
#define SG_B(SBUF, H, KT) do { \
    GLDS16(gB[H][0] + ((size_t)(KT) << 6), SBUF + ((H) * 128 + w16o2) * 64); \
    GLDS16(gB[H][1] + ((size_t)(KT) << 6), SBUF + ((H) * 128 + w16o2 + 8) * 64); \
  } while (0)

#define DS_B(PB_) do { \
  bf00 = *(const short8*)(PB_ + 0    + cks0); bf01 = *(const short8*)(PB_ + 1024 + cks0); \
  bf02 = *(const short8*)(PB_ + 2048 + cks0); bf03 = *(const short8*)(PB_ + 3072 + cks0); \
  bf10 = *(const short8*)(PB_ + 0    + cks1); bf11 = *(const short8*)(PB_ + 1024 + cks1); \
  bf12 = *(const short8*)(PB_ + 2048 + cks1); bf13 = *(const short8*)(PB_ + 3072 + cks1); \
} while (0)

#define P_CORE(PA_, MQ, KS, STAGE_STMT, GATE_STMT) do { \
  af0 = *(const short8*)(PA_ + (MQ) * 4096 + 0    + cks##KS); \
  af1 = *(const short8*)(PA_ + (MQ) * 4096 + 1024 + cks##KS); \
  af2 = *(const short8*)(PA_ + (MQ) * 4096 + 2048 + cks##KS); \
  af3 = *(const short8*)(PA_ + (MQ) * 4096 + 3072 + cks##KS); \
  STAGE_STMT; \
  __builtin_amdgcn_s_barrier(); \
  asm volatile("s_waitcnt lgkmcnt(0)" ::: "memory"); \
  __builtin_amdgcn_sched_barrier(0); \
  __builtin_amdgcn_s_setprio(1); \
  MFMA16(MQ, KS); \
  __builtin_amdgcn_s_setprio(0); \
  GATE_STMT; \
  __builtin_amdgcn_s_barrier(); \
} while (0)

#define GATE6 asm volatile("s_waitcnt vmcnt(6)" ::: "memory")
#define GATE0 asm volatile("s_waitcnt vmcnt(0)" ::: "memory")

template<int MODE>
__global__ __launch_bounds__(512, 2) void gemm8p(
    const u16* __restrict__ A, const u16* __restrict__ BT, void* __restrict__ C,
    int M, int N, int Ktot, int Kslice)
{
  __shared__ u16 sh[2][2][16384]; // [buf][A/B][256*64]
  const int nbn = N >> 8;
  const int nwg = gridDim.x;
  int bid = blockIdx.x;
  bid = (bid & 7) * (nwg >> 3) + (bid >> 3);   // bijective XCD swizzle (nwg % 8 == 0)
  const int bm = bid / nbn, bn = bid % nbn;
  const int kbase = blockIdx.y * Kslice;
  const int NI = Kslice >> 7;

  const int t = threadIdx.x, w = t >> 6, lane = t & 63;
  const int wr = w >> 2, wc = w & 3;
  const int lr = lane & 15, lg = lane >> 4;
  const int r8 = lane >> 3, ch = lane & 7;
  const int clog = ch ^ r8;                     // inverse-swizzled source chunk
  const int w16o  = w * 16 + ((w >= 4) ? 64 : 0); // A-half row offset for this wave's 2 issues
  const int w16o2 = w * 16;                        // B-half row offset (contiguous 128 rows)

  const u16* gA[2][2]; const u16* gB[2][2];
  #pragma unroll
  for (int h = 0; h < 2; ++h)
    #pragma unroll
    for (int qq = 0; qq < 2; ++qq) {
      gA[h][qq] = A  + (size_t)(bm * 256 + h * 64  + w16o  + qq * 8 + r8) * Ktot + kbase + clog * 8;
      gB[h][qq] = BT + (size_t)(bn * 256 + h * 128 + w16o2 + qq * 8 + r8) * Ktot + kbase + clog * 8;
    }
  u16* sA0 = &sh[0][0][0]; u16* sA1 = &sh[1][0][0];
  u16* sB0 = &sh[0][1][0]; u16* sB1 = &sh[1][1][0];
  const int cks0 = ((0 + lg) ^ (lr & 7)) * 8;
  const int cks1 = ((4 + lg) ^ (lr & 7)) * 8;
  const u16* pA_b0 = sA0 + (wr * 128 + lr) * 64;
  const u16* pA_b1 = sA1 + (wr * 128 + lr) * 64;
  const u16* pB_b0 = sB0 + (wc * 64 + lr) * 64;
  const u16* pB_b1 = sB1 + (wc * 64 + lr) * 64;

  f32x4 acc[2][4][4];
  const f32x4 z4 = { 0.f, 0.f, 0.f, 0.f };
  #pragma unroll
  for (int a = 0; a < 2; ++a)
    #pragma unroll
    for (int b = 0; b < 4; ++b)
      #pragma unroll
      for (int c = 0; c < 4; ++c) acc[a][b][c] = z4;
  short8 af0, af1, af2, af3;
  short8 bf00, bf01, bf02, bf03, bf10, bf11, bf12, bf13;

  // prologue: tile0 -> buf0 (4 halves), tile1 -> buf1 (B0,B1,A0); A1(1) staged at first P0
  SG_B(sB0, 0, 0); SG_B(sB0, 1, 0); SG_A(sA0, 0, 0); SG_A(sA0, 1, 0);
  SG_B(sB1, 0, 1); SG_B(sB1, 1, 1); SG_A(sA1, 0, 1);
  GATE6;
  __builtin_amdgcn_s_barrier();

  for (int i = 0; i < NI; ++i) {
    const int k2 = 2 * i;
    const bool st = (i < NI - 1);
    // P0 (buf0, mq0, ks0) + all B(buf0)
    DS_B(pB_b0);
    P_CORE(pA_b0, 0, 0, SG_A(sA1, 1, k2 + 1), );
    // P1 (buf0, mq1, ks0)
    P_CORE(pA_b0, 1, 0, if (st) SG_B(sB0, 0, k2 + 2), );
    // P2 (buf0, mq0, ks1)
    P_CORE(pA_b0, 0, 1, if (st) SG_B(sB0, 1, k2 + 2), );
    // P3 (buf0, mq1, ks1) + gate for buf1
    P_CORE(pA_b0, 1, 1, if (st) SG_A(sA0, 0, k2 + 2),
           if (st) { GATE6; } else { GATE0; });
    // P4 (buf1, mq0, ks0) + all B(buf1)
    DS_B(pB_b1);
    P_CORE(pA_b1, 0, 0, if (st) SG_A(sA0, 1, k2 + 2), );
    // P5 (buf1, mq1, ks0)
    P_CORE(pA_b1, 1, 0, if (st) SG_B(sB1, 0, k2 + 3), );
    // P6 (buf1, mq0, ks1)
    P_CORE(pA_b1, 0, 1, if (st) SG_B(sB1, 1, k2 + 3), );
    // P7 (buf1, mq1, ks1) + gate for next buf0
    P_CORE(pA_b1, 1, 1, if (st) SG_A(sA1, 0, k2 + 3),
           if (st) { GATE6; });
  }

  if constexpr (MODE == 0) {
    u16* Co = (u16*)C;
    #pragma unroll
    for (int mq = 0; mq < 2; ++mq)
      #pragma unroll
      for (int m = 0; m < 4; ++m)
        #pragma unroll
        for (int n = 0; n < 4; ++n)
          #pragma unroll
          for (int rr = 0; rr < 4; ++rr) {
            const int row = bm * 256 + wr * 128 + mq * 64 + m * 16 + lg * 4 + rr;
            const int col = bn * 256 + wc * 64 + n * 16 + lr;
            Co[(size_t)row * N + col] = f2bf(acc[mq][m][n][rr]);
          }
  } else {
    float* Co = (float*)C + (size_t)blockIdx.y * M * N;
    #pragma unroll
    for (int mq = 0; mq < 2; ++mq)
      #pragma unroll
      for (int m = 0; m < 4; ++m)
        #pragma unroll
        for (int n = 0; n < 4; ++n)
          #pragma unroll
          for (int rr = 0; rr < 4; ++rr) {
            const int row = bm * 256 + wr * 128 + mq * 64 + m * 16 + lg * 4 + rr;
            const int col = bn * 256 + wc * 64 + n * 16 + lr;
            Co[(size_t)row * N + col] = acc[mq][m][n][rr];
          }
  }
}

// ---------------- split-K GEMM 128x128 (kept for the tiny kv projection) ----------------
__global__ __launch_bounds__(256) void gemm_bt_sk(
    const u16* __restrict__ A, const u16* __restrict__ BT, float* __restrict__ Cp,
    int M, int N, int Kslice, int Ktot)
{
  __shared__ u16 As[128 * 32];
  __shared__ u16 Bs[128 * 32];
  const int bm = blockIdx.y, bn = blockIdx.x, z = blockIdx.z;
  const int t = threadIdx.x;
  const int w = t >> 6, lane = t & 63;
  const int wr = w >> 1, wc = w & 1;
  const int lr = lane & 15, lkc = lane >> 4;

  f32x4 acc[4][4];
  const f32x4 z4 = { 0.f, 0.f, 0.f, 0.f };
  #pragma unroll
  for (int mi = 0; mi < 4; ++mi)
    #pragma unroll
    for (int ni = 0; ni < 4; ++ni) acc[mi][ni] = z4;

  const int kbase = z * Kslice;
  const int i0 = t, i1 = t + 256;
  const int r0 = i0 >> 2, k0 = swz4(r0, i0 & 3) * 8;
  const int r1 = i1 >> 2, k1 = swz4(r1, i1 & 3) * 8;
  const u16* a0 = A + (size_t)(bm * 128 + r0) * Ktot + kbase + k0;
  const u16* a1 = A + (size_t)(bm * 128 + r1) * Ktot + kbase + k1;
  const u16* b0 = BT + (size_t)(bn * 128 + r0) * Ktot + kbase + k0;
  const u16* b1 = BT + (size_t)(bn * 128 + r1) * Ktot + kbase + k1;
  u16* As0 = As + (size_t)w * 512;
  u16* As1 = As + (size_t)(w + 4) * 512;
  u16* Bs0 = Bs + (size_t)w * 512;
  u16* Bs1 = Bs + (size_t)(w + 4) * 512;

  const int nk = Kslice >> 5;
  for (int kt = 0; kt < nk; ++kt) {
    __syncthreads();
    GLDS16(a0, As0); GLDS16(a1, As1); GLDS16(b0, Bs0); GLDS16(b1, Bs1);
    a0 += 32; a1 += 32; b0 += 32; b1 += 32;
    __syncthreads();
    short8 af[4], bf[4];
    #pragma unroll
    for (int mi = 0; mi < 4; ++mi) {
      int row = wr * 64 + mi * 16 + lr;
      af[mi] = *(const short8*)&As[row * 32 + swz4(row, lkc) * 8];
    }
    #pragma unroll
    for (int ni = 0; ni < 4; ++ni) {
      int row = wc * 64 + ni * 16 + lr;
      bf[ni] = *(const short8*)&Bs[row * 32 + swz4(row, lkc) * 8];
    }
    #pragma unroll
    for (int mi = 0; mi < 4; ++mi)
      #pragma unroll
      for (int ni = 0; ni < 4; ++ni)
        acc[mi][ni] = __builtin_amdgcn_mfma_f32_16x16x32_bf16(af[mi], bf[ni], acc[mi][ni], 0, 0, 0);
  }

  float* Cz = Cp + (size_t)z * M * N;
  const int row0 = bm * 128 + wr * 64, col0 = bn * 128 + wc * 64;
  const int rsub = (lane >> 4) * 4;
  #pragma unroll
  for (int mi = 0; mi < 4; ++mi)
    #pragma unroll
    for (int ni = 0; ni < 4; ++ni)
      #pragma unroll
      for (int r = 0; r < 4; ++r)
        Cz[(size_t)(row0 + mi * 16 + rsub + r) * N + (col0 + ni * 16 + lr)] = acc[mi][ni][r];
}

// ---------------- reduce 8 f32 partials (4096x128) -> bf16 ----------------
__global__ __launch_bounds__(256) void reduce_kv(const float* __restrict__ part, u16* __restrict__ out)
{
  const size_t base = ((size_t)blockIdx.x * 256 + threadIdx.x) * 4;
  f32x4 s = *(const f32x4*)&part[base];
  #pragma unroll
  for (int zz = 1; zz < 8; ++zz) {
    const f32x4 v = *(const f32x4*)&part[(size_t)zz * 524288 + base];
    s[0] += v[0]; s[1] += v[1]; s[2] += v[2]; s[3] += v[3];
  }
  uint2 pv;
  pv.x = (unsigned)f2bf(s[0]) | ((unsigned)f2bf(s[1]) << 16);
  pv.y = (unsigned)f2bf(s[2]) | ((unsigned)f2bf(s[3]) << 16);
  *(uint2*)&out[base] = pv;
}

// ---------------- out = sum of 4 f32 partials (4096x1024) ----------------
__global__ __launch_bounds__(256) void reduce_out(const float* __restrict__ part, float* __restrict__ out)
{
  const size_t base = ((size_t)blockIdx.x * 256 + threadIdx.x) * 4;
  f32x4 s = *(const f32x4*)&part[base];
  #pragma unroll
  for (int zz = 1; zz < 4; ++zz) {
    const f32x4 v = *(const f32x4*)&part[(size_t)zz * 4194304 + base];
    s[0] += v[0]; s[1] += v[1]; s[2] += v[2]; s[3] += v[3];
  }
  *(f32x4*)&out[base] = s;
}

// ---------------- flash cross-attention (multi-query: 1 KV head) ----------------
// q: cols 0..1023 of qff (row stride 9216), pre-scaled. o -> aoh cols 0..1023 (row stride 5120)
__global__ __launch_bounds__(256) void attn_kernel(
    const u16* __restrict__ q, const u16* __restrict__ kv, u16* __restrict__ o)
{
  __shared__ u16 Ks[128 * 64];
  __shared__ u16 Vt[64 * 128];
  __shared__ u16 Ps[4][32 * 128];
  const int b = blockIdx.z, hb = blockIdx.y, qb = blockIdx.x;
  const int t = threadIdx.x, w = t >> 6, lane = t & 63;
  const int q32 = lane & 31, hl = lane >> 5;
  const int hd = hb * 4 + w;

  const size_t qbase = (size_t)b * 2048 + qb * 64;
  short8 qa[2][4];
  #pragma unroll
  for (int t32 = 0; t32 < 2; ++t32)
    #pragma unroll
    for (int dq = 0; dq < 4; ++dq)
      qa[t32][dq] = *(const short8*)&q[(qbase + t32 * 32 + q32) * 9216 + hd * 64 + dq * 16 + hl * 8];

  f32x16 oacc[2][2];
  #pragma unroll
  for (int i = 0; i < 2; ++i)
    #pragma unroll
    for (int j = 0; j < 2; ++j)
      #pragma unroll
      for (int r = 0; r < 16; ++r) oacc[i][j][r] = 0.f;
  float m_[2] = { -1e30f, -1e30f }, l_[2] = { 0.f, 0.f };

  const size_t kvb = (size_t)b * 2048 * 128;
  const int vd0 = (t & 7) * 8;
  const int vodd = (t >> 3) & 1;
  u16* Pw = &Ps[w][0];

  for (int jt = 0; jt < 16; ++jt) {
    __syncthreads();
    #pragma unroll
    for (int n = 0; n < 4; ++n) {
      const int cc = n * 256 + w * 64;
      const int ccl = cc + lane;
      const int row = ccl >> 3, lc = (ccl & 7) ^ (row & 7);
      GLDS16(&kv[kvb + (size_t)(jt * 128 + row) * 128 + lc * 8], Ks + (size_t)cc * 8);
    }
    #pragma unroll
    for (int c = 0; c < 4; ++c) {
      const int seg = c * 256 + t;
      const int vj = seg >> 3;
      const int jp = vj >> 1;
      const uint4 vv = *(const uint4*)&kv[kvb + (size_t)(jt * 128 + vj) * 128 + 64 + vd0];
      uint4 pvv;
      pvv.x = __shfl_xor((int)vv.x, 8);
      pvv.y = __shfl_xor((int)vv.y, 8);
      pvv.z = __shfl_xor((int)vv.z, 8);
      pvv.w = __shfl_xor((int)vv.w, 8);
      const unsigned ow[4] = { vv.x, vv.y, vv.z, vv.w };
      const unsigned pw[4] = { pvv.x, pvv.y, pvv.z, pvv.w };
      if (!vodd) {
        #pragma unroll
        for (int u = 0; u < 4; ++u) {
          const int d = vd0 + u;
          const unsigned own = (u & 1) ? (ow[u >> 1] >> 16) : (ow[u >> 1] & 0xffffu);
          const unsigned par = (u & 1) ? (pw[u >> 1] >> 16) : (pw[u >> 1] & 0xffffu);
          const int byteoff = d * 256 + ((4 * jp) ^ (((d & 7) ^ ((d >> 3) & 7)) << 4));
          *(unsigned*)((char*)Vt + byteoff) = own | (par << 16);
        }
      } else {
        #pragma unroll
        for (int u = 0; u < 4; ++u) {
          const int ue = u + 4;
          const int d = vd0 + ue;
          const unsigned own = (ue & 1) ? (ow[ue >> 1] >> 16) : (ow[ue >> 1] & 0xffffu);
          const unsigned par = (ue & 1) ? (pw[ue >> 1] >> 16) : (pw[ue >> 1] & 0xffffu);
          const int byteoff = d * 256 + ((4 * jp) ^ (((d & 7) ^ ((d >> 3) & 7)) << 4));
          *(unsigned*)((char*)Vt + byteoff) = par | (own << 16);
        }
      }
    }
    __syncthreads();

    #pragma unroll
    for (int t32 = 0; t32 < 2; ++t32) {
      f32x16 s[4];
      #pragma unroll
      for (int j32 = 0; j32 < 4; ++j32)
        #pragma unroll
        for (int r = 0; r < 16; ++r) s[j32][r] = 0.f;
      #pragma unroll
      for (int j32 = 0; j32 < 4; ++j32) {
        const int row = j32 * 32 + q32;
        #pragma unroll
        for (int dq = 0; dq < 4; ++dq) {
          const int slot = (dq * 2 + hl) ^ (row & 7);
          const short8 kf = *(const short8*)&Ks[row * 64 + slot * 8];
          s[j32] = __builtin_amdgcn_mfma_f32_32x32x16_bf16(kf, qa[t32][dq], s[j32], 0, 0, 0);
        }
      }
      float mt = -1e30f;
      #pragma unroll
      for (int j32 = 0; j32 < 4; ++j32)
        #pragma unroll
        for (int r = 0; r < 16; ++r) mt = fmaxf(mt, s[j32][r]);
      mt = fmaxf(mt, __shfl_xor(mt, 32));
      const float nm = fmaxf(m_[t32], mt);
      const float alpha = __expf(m_[t32] - nm);
      m_[t32] = nm;
      float lsum = 0.f;
      #pragma unroll
      for (int j32 = 0; j32 < 4; ++j32) {
        float p[16];
        #pragma unroll
        for (int r = 0; r < 16; ++r) { p[r] = __expf(s[j32][r] - nm); lsum += p[r]; }
        #pragma unroll
        for (int g = 0; g < 4; ++g) {
          const unsigned lo = cvtpk(p[4 * g + 0], p[4 * g + 1]);
          const unsigned hi = cvtpk(p[4 * g + 2], p[4 * g + 3]);
          const int j2 = j32 * 64 + 16 * g + 8 * hl;
          const int byteoff = q32 * 256 + (j2 ^ ((q32 & 7) << 4));
          uint2 wv; wv.x = lo; wv.y = hi;
          *(uint2*)((char*)Pw + byteoff) = wv;
        }
      }
      lsum += __shfl_xor(lsum, 32);
      l_[t32] = l_[t32] * alpha + lsum;
      #pragma unroll
      for (int d32 = 0; d32 < 2; ++d32)
        #pragma unroll
        for (int r = 0; r < 16; ++r) oacc[t32][d32][r] *= alpha;
      short8 pf[8];
      #pragma unroll
      for (int kk = 0; kk < 8; ++kk) {
        const int byteoff = q32 * 256 + ((kk * 32 + hl * 16) ^ ((q32 & 7) << 4));
        pf[kk] = *(const short8*)((const char*)Pw + byteoff);
      }
      #pragma unroll
      for (int d32 = 0; d32 < 2; ++d32) {
        const int dr = d32 * 32 + q32;
        const int vswz = ((dr & 7) ^ ((dr >> 3) & 7)) << 4;
        #pragma unroll
        for (int kk = 0; kk < 8; ++kk) {
          const int byteoff = dr * 256 + ((kk * 32 + hl * 16) ^ vswz);
          const short8 vf = *(const short8*)((const char*)Vt + byteoff);
          oacc[t32][d32] = __builtin_amdgcn_mfma_f32_32x32x16_bf16(vf, pf[kk], oacc[t32][d32], 0, 0, 0);
        }
      }
    }
  }

  float* Ot = (float*)Pw;
  #pragma unroll
  for (int t32 = 0; t32 < 2; ++t32) {
    const float inv = 1.0f / l_[t32];
    #pragma unroll
    for (int d32 = 0; d32 < 2; ++d32) {
      #pragma unroll
      for (int r = 0; r < 16; ++r) {
        const int d = (r & 3) + 8 * (r >> 2) + 4 * hl;
        const int byteoff = q32 * 128 + ((4 * d) ^ ((q32 & 7) << 4));
        *(float*)((char*)Ot + byteoff) = oacc[t32][d32][r] * inv;
      }
      const int qr = lane >> 1, dc = (lane & 1) * 16;
      union { u16 s[16]; uint4 v[2]; } ob;
      #pragma unroll
      for (int cch = 0; cch < 4; ++cch) {
        const int byteoff = qr * 128 + ((4 * (dc + 4 * cch)) ^ ((qr & 7) << 4));
        const f32x4 vv = *(const f32x4*)((const char*)Ot + byteoff);
        ob.s[cch * 4 + 0] = f2bf(vv[0]);
        ob.s[cch * 4 + 1] = f2bf(vv[1]);
        ob.s[cch * 4 + 2] = f2bf(vv[2]);
        ob.s[cch * 4 + 3] = f2bf(vv[3]);
      }
      u16* orow = &o[(qbase + t32 * 32 + qr) * 5120 + hd * 64 + d32 * 32 + dc];
      *(uint4*)orow = ob.v[0];
      *(uint4*)(orow + 8) = ob.v[1];
    }
  }
}

// ---------------- silu(gate)*a from qff -> aoh cols 1024.. (row stride 5120) ----------------
__global__ __launch_bounds__(256) void silu_kernel(const u16* __restrict__ qff, u16* __restrict__ aoh)
{
  const size_t i = (size_t)blockIdx.x * 256 + threadIdx.x;
  const size_t row = i >> 9;
  const size_t c8 = (i & 511) * 8;
  const short8 av = *(const short8*)&qff[row * 9216 + 1024 + c8];
  const short8 gv = *(const short8*)&qff[row * 9216 + 5120 + c8];
  union { u16 s[8]; uint4 v; } pk;
  #pragma unroll
  for (int u = 0; u < 8; ++u) {
    const float gg = bf2f((u16)gv[u]);
    const float aa = bf2f((u16)av[u]);
    const float sg = gg / (1.0f + __expf(-gg));
    pk.s[u] = f2bf(sg * aa);
  }
  *(uint4*)&aoh[row * 5120 + 1024 + c8] = pk.v;
}

extern "C" void kernel_launch(void* const* d_in, const int* in_sizes, int n_in,
                              void* d_out, int out_size, void* d_ws, size_t ws_size,
                              hipStream_t stream)
{
  const float* x    = (const float*)d_in[0];
  const float* ctx  = (const float*)d_in[1];
  const float* ng   = (const float*)d_in[2];
  const float* nb   = (const float*)d_in[3];
  const float* cg   = (const float*)d_in[4];
  const float* cb   = (const float*)d_in[5];
  const float* Wq   = (const float*)d_in[6];
  const float* Wkv  = (const float*)d_in[7];
  const float* Wo   = (const float*)d_in[8];
  const float* Wff1 = (const float*)d_in[9];
  const float* Wff2 = (const float*)d_in[10];

  u16* p = (u16*)d_ws;
  u16* W1T   = p; p += (size_t)9216 * 1024;   // [Wq*0.125 | Wff1]^T
  u16* WkvT  = p; p += (size_t)128 * 1024;
  u16* WcT   = p; p += (size_t)1024 * 5120;   // [Wo ; Wff2]^T rows n, k=0..5119
  u16* xn    = p; p += (size_t)4096 * 1024;
  u16* cn    = p; p += (size_t)4096 * 1024;
  u16* qff   = p; p += (size_t)4096 * 9216;   // q | a | gate
  u16* kvbuf = p; p += (size_t)4096 * 128;
  u16* aoh   = p; p += (size_t)4096 * 5120;   // [attn_out | silu] fused A for final GEMM
  float* kvpart = (float*)aoh;                 // 16 MB, consumed before aoh written
  float* ffpart = (float*)qff;                 // 64 MB, qff dead after attn+silu
  (void)in_sizes; (void)n_in; (void)out_size; (void)ws_size;

  ln_kernel<<<8192, 256, 0, stream>>>(x, ctx, ng, nb, cg, cb, xn, cn);

  transpose_k<<<dim3(16, 16),  256, 0, stream>>>(Wq,   W1T,                       1024, 1024, 1024, 0.125f);
  transpose_k<<<dim3(128, 16), 256, 0, stream>>>(Wff1, W1T + (size_t)1024 * 1024, 1024, 8192, 1024, 1.0f);
  transpose_k<<<dim3(2, 16),   256, 0, stream>>>(Wkv,  WkvT, 1024, 128,  1024, 1.0f);
  transpose_k<<<dim3(16, 16),  256, 0, stream>>>(Wo,   WcT,                1024, 1024, 5120, 1.0f);
  transpose_k<<<dim3(16, 64),  256, 0, stream>>>(Wff2, WcT + 1024,         4096, 1024, 5120, 1.0f);

  // qff = xn @ [Wq*scale | Wff1]   (4096 x 9216 x 1024), 576 blocks, 8-phase
  gemm8p<0><<<dim3(576), 512, 0, stream>>>(xn, W1T, qff, 4096, 9216, 1024, 1024);
  // kv = cn @ Wkv, split-K 8 -> partials aliased over aoh, reduce to bf16
  gemm_bt_sk<<<dim3(1, 32, 8), 256, 0, stream>>>(cn, WkvT, kvpart, 4096, 128, 128, 1024);
  reduce_kv<<<512, 256, 0, stream>>>(kvpart, kvbuf);
  // silu -> aoh[:,1024:]
  silu_kernel<<<8192, 256, 0, stream>>>(qff, aoh);
  // attention -> aoh[:,0:1024]
  attn_kernel<<<dim3(32, 4, 2), 256, 0, stream>>>(qff, kvbuf, aoh);
  // out = aoh @ [Wo ; Wff2]  (4096 x 1024 x 5120), split-K 4, 8-phase, f32 partials
  gemm8p<1><<<dim3(64, 4), 512, 0, stream>>>(aoh, WcT, ffpart, 4096, 1024, 5120, 1280);
  reduce_out<<<4096, 256, 0, stream>>>(ffpart, (float*)d_out);
}

// Round 5
// 302.102 us; speedup vs baseline: 1.5717x; 1.0468x over previous
//
#include <hip/hip_runtime.h>
#include <stdint.h>

typedef unsigned short u16;
typedef __attribute__((ext_vector_type(8))) short short8;
typedef __attribute__((ext_vector_type(4))) float f32x4;
typedef __attribute__((ext_vector_type(16))) float f32x16;

#define GPTR(p) ((const __attribute__((address_space(1))) void*)(p))
#define SPTR(p) ((__attribute__((address_space(3))) void*)(p))
#define GLDS16(g, l) __builtin_amdgcn_global_load_lds(GPTR(g), SPTR(l), 16, 0, 0)

static __device__ __forceinline__ float bf2f(u16 u) {
  union { unsigned int i; float f; } c; c.i = ((unsigned int)u) << 16; return c.f;
}
static __device__ __forceinline__ u16 f2bf(float f) {
  union { float f; unsigned int u; } c; c.f = f;
  unsigned int r = 0x7fffu + ((c.u >> 16) & 1u);
  return (u16)((c.u + r) >> 16);
}
static __device__ __forceinline__ unsigned cvtpk(float a, float b) {
  unsigned r;
  asm volatile("v_cvt_pk_bf16_f32 %0, %1, %2" : "=v"(r) : "v"(a), "v"(b));
  return r;
}
static __device__ __forceinline__ int swz4(int row, int c) { return c ^ ((row >> 1) & 3); }

// ---------------- LayerNorm: f32 (rows of 1024) -> bf16 ----------------
__global__ __launch_bounds__(256) void ln_kernel(
    const float* __restrict__ x, const float* __restrict__ ctx,
    const float* __restrict__ g, const float* __restrict__ b,
    const float* __restrict__ cg, const float* __restrict__ cb,
    u16* __restrict__ xn, u16* __restrict__ cn)
{
  const int row = blockIdx.x;
  const float* src; const float* gg; const float* bb; u16* dst;
  if (row < 4096) { src = x + (size_t)row * 1024; gg = g;  bb = b;  dst = xn + (size_t)row * 1024; }
  else            { src = ctx + (size_t)(row - 4096) * 1024; gg = cg; bb = cb; dst = cn + (size_t)(row - 4096) * 1024; }
  const int t = threadIdx.x;
  float4 v = *(const float4*)&src[t * 4];
  float s  = v.x + v.y + v.z + v.w;
  float s2 = v.x * v.x + v.y * v.y + v.z * v.z + v.w * v.w;
  #pragma unroll
  for (int off = 1; off < 64; off <<= 1) { s += __shfl_xor(s, off); s2 += __shfl_xor(s2, off); }
  __shared__ float ls[4], ls2[4];
  const int w = t >> 6;
  if ((t & 63) == 0) { ls[w] = s; ls2[w] = s2; }
  __syncthreads();
  s  = ls[0] + ls[1] + ls[2] + ls[3];
  s2 = ls2[0] + ls2[1] + ls2[2] + ls2[3];
  const float mu   = s * (1.0f / 1024.0f);
  const float var  = s2 * (1.0f / 1024.0f) - mu * mu;
  const float rstd = rsqrtf(var + 1e-5f);
  float xv[4] = { v.x, v.y, v.z, v.w };
  u16 o[4];
  #pragma unroll
  for (int i = 0; i < 4; ++i)
    o[i] = f2bf((xv[i] - mu) * rstd * gg[t * 4 + i] + bb[t * 4 + i]);
  uint2 pv;
  pv.x = (unsigned)o[0] | ((unsigned)o[1] << 16);
  pv.y = (unsigned)o[2] | ((unsigned)o[3] << 16);
  *(uint2*)&dst[t * 4] = pv;
}

// ---------------- transpose+convert: f32 (R,C) -> bf16 (C,R) with out leading dim ----------------
__global__ __launch_bounds__(256) void transpose_k(
    const float* __restrict__ in, u16* __restrict__ out, int R, int C, int ldo, float scale)
{
  __shared__ float tile[64][65];
  const int c0 = blockIdx.x * 64, r0 = blockIdx.y * 64;
  const int t = threadIdx.x;
  const int tr = t >> 4, tc = (t & 15) * 4;
  #pragma unroll
  for (int i = 0; i < 4; ++i) {
    int r = tr + i * 16;
    float4 v = *(const float4*)&in[(size_t)(r0 + r) * C + c0 + tc];
    tile[r][tc + 0] = v.x; tile[r][tc + 1] = v.y; tile[r][tc + 2] = v.z; tile[r][tc + 3] = v.w;
  }
  __syncthreads();
  #pragma unroll
  for (int i = 0; i < 2; ++i) {
    int c  = (t >> 3) + i * 32;
    int rb = (t & 7) * 8;
    union { u16 s[8]; uint4 v; } pk;
    #pragma unroll
    for (int u = 0; u < 8; ++u) pk.s[u] = f2bf(tile[rb + u][c] * scale);
    *(uint4*)&out[(size_t)(c0 + c) * ldo + r0 + rb] = pk.v;
  }
}

// ---------------- Wff1 transpose with (a,gate) fragment interleave ----------------
// in: Wff1 (1024, 8192) f32, col c<4096 = a_j (j=c), c>=4096 = gate_j.
// out row for a_j    = 1024 + (j>>7)*256 + ((j>>5)&3)*64 + ((j>>4)&1)*32 + (j&15)
// out row for gate_j = same + 16   (so GEMM tile frag n=2*n2 is a, n=2*n2+1 its gate)
__global__ __launch_bounds__(256) void transpose_ff1(
    const float* __restrict__ in, u16* __restrict__ out)
{
  __shared__ float tile[64][65];
  const int c0 = blockIdx.x * 64, r0 = blockIdx.y * 64;
  const int t = threadIdx.x;
  const int tr = t >> 4, tc = (t & 15) * 4;
  #pragma unroll
  for (int i = 0; i < 4; ++i) {
    int r = tr + i * 16;
    float4 v = *(const float4*)&in[(size_t)(r0 + r) * 8192 + c0 + tc];
    tile[r][tc + 0] = v.x; tile[r][tc + 1] = v.y; tile[r][tc + 2] = v.z; tile[r][tc + 3] = v.w;
  }
  __syncthreads();
  #pragma unroll
  for (int i = 0; i < 2; ++i) {
    int c  = (t >> 3) + i * 32;
    int rb = (t & 7) * 8;
    const int gc = c0 + c;
    int j, add16;
    if (gc < 4096) { j = gc; add16 = 0; } else { j = gc - 4096; add16 = 16; }
    const int row = 1024 + ((j >> 7) << 8) + (((j >> 5) & 3) << 6) + (((j >> 4) & 1) << 5) + add16 + (j & 15);
    union { u16 s[8]; uint4 v; } pk;
    #pragma unroll
    for (int u = 0; u < 8; ++u) pk.s[u] = f2bf(tile[rb + u][c]);
    *(uint4*)&out[(size_t)row * 1024 + r0 + rb] = pk.v;
  }
}

// =============== 8-phase 256x256 GEMM (BK=64, 8 waves, 2-deep dbuf) ===============
// C(M,N) = A(M,Ktot)[:, kb:kb+Kslice] * BT(N,Ktot)[:, kb:kb+Kslice]^T, kb = blockIdx.y*Kslice
// MODE 1: f32 store to C + blockIdx.y*M*N (split-K partials), C2 unused.
// MODE 2: qff fused epilogue: bn<4 -> bf16 q to C (stride 1024); bn>=4 -> silu(gate)*a
//         pair-fused h to C2 (aoh, stride 5120, col 1024 + (bn-4)*128 + wc*32 + n2*16 + lr).
// Schedule = m201 template: per phase {ds_read subtile ; stage ; [lgkm hint] ; barrier ;
// lgkmcnt(0) ; setprio1 ; 16 MFMA ; setprio0 ; [vmcnt gate at P3/P7] ; barrier}. No sched_barrier.
#define MM1(MQ, M, NN, BF) acc[MQ][M][NN] = __builtin_amdgcn_mfma_f32_16x16x32_bf16(af##M, BF, acc[MQ][M][NN], 0, 0, 0)
#define MFMA16(MQ, KS) \
  MM1(MQ,0,0,bf##KS##0); MM1(MQ,0,1,bf##KS##1); MM1(MQ,0,2,bf##KS##2); MM1(MQ,0,3,bf##KS##3); \
  MM1(MQ,1,0,bf##KS##0); MM1(MQ,1,1,bf##KS##1); MM1(MQ,1,2,bf##KS##2); MM1(MQ,1,3,bf##KS##3); \
  MM1(MQ,2,0,bf##KS##0); MM1(MQ,2,1,bf##KS##1); MM1(MQ,2,2,bf##KS##2); MM1(MQ,2,3,bf##KS##3); \
  MM1(MQ,3,0,bf##KS##0); MM1(MQ,3,1,bf##KS##1); MM1(MQ,3,2,bf##KS##2); MM1(MQ,3,3,bf##KS##3)

#define SG_A(SBUF, H, KT) do { \
    GLDS16(gA[H][0] + ((size_t)(KT) << 6), SBUF + ((H) * 64 + w16o) * 64); \
    GLDS16(gA[H][1] + ((size_t)(KT) << 6), SBUF + ((H) * 64 + w16o + 8) * 64); \
  } while (0)
#define SG_B(SBUF, H, KT) do { \
    GLDS16(gB[H][0] + ((size_t)(KT) << 6), SBUF + ((H) * 128 + w16o2) * 64); \
    GLDS16(gB[H][1] + ((size_t)(KT) << 6), SBUF + ((H) * 128 + w16o2 + 8) * 64); \
  } while (0)

#define DS_B(PB_) do { \
  bf00 = *(const short8*)(PB_ + 0    + cks0); bf01 = *(const short8*)(PB_ + 1024 + cks0); \
  bf02 = *(const short8*)(PB_ + 2048 + cks0); bf03 = *(const short8*)(PB_ + 3072 + cks0); \
  bf10 = *(const short8*)(PB_ + 0    + cks1); bf11 = *(const short8*)(PB_ + 1024 + cks1); \
  bf12 = *(const short8*)(PB_ + 2048 + cks1); bf13 = *(const short8*)(PB_ + 3072 + cks1); \
} while (0)

#define P_CORE(PA_, MQ, KS, STAGE_STMT, PREB_STMT, GATE_STMT) do { \
  af0 = *(const short8*)(PA_ + (MQ) * 4096 + 0    + cks##KS); \
  af1 = *(const short8*)(PA_ + (MQ) * 4096 + 1024 + cks##KS); \
  af2 = *(const short8*)(PA_ + (MQ) * 4096 + 2048 + cks##KS); \
  af3 = *(const short8*)(PA_ + (MQ) * 4096 + 3072 + cks##KS); \
  STAGE_STMT; \
  PREB_STMT; \
  __builtin_amdgcn_s_barrier(); \
  asm volatile("s_waitcnt lgkmcnt(0)" ::: "memory"); \
  __builtin_amdgcn_s_setprio(1); \
  MFMA16(MQ, KS); \
  __builtin_amdgcn_s_setprio(0); \
  GATE_STMT; \
  __builtin_amdgcn_s_barrier(); \
} while (0)

#define GATE6 asm volatile("s_waitcnt vmcnt(6)" ::: "memory")
#define GATE0 asm volatile("s_waitcnt vmcnt(0)" ::: "memory")
#define HINT8 asm volatile("s_waitcnt lgkmcnt(8)" ::: "memory")

template<int MODE>
__global__ __launch_bounds__(512, 2) void gemm8p(
    const u16* __restrict__ A, const u16* __restrict__ BT, void* __restrict__ C,
    void* __restrict__ C2, int M, int N, int Ktot, int Kslice)
{
  __shared__ u16 sh[2][2][16384]; // [buf][A/B][256*64]
  const int nbn = N >> 8;
  const int nwg = gridDim.x;
  int bid = blockIdx.x;
  bid = (bid & 7) * (nwg >> 3) + (bid >> 3);   // bijective XCD swizzle (nwg % 8 == 0)
  const int bm = bid / nbn, bn = bid % nbn;
  const int kbase = blockIdx.y * Kslice;
  const int NI = Kslice >> 7;

  const int t = threadIdx.x, w = t >> 6, lane = t & 63;
  const int wr = w >> 2, wc = w & 3;
  const int lr = lane & 15, lg = lane >> 4;
  const int r8 = lane >> 3, ch = lane & 7;
  const int clog = ch ^ r8;                      // inverse-swizzled source chunk
  const int w16o  = w * 16 + ((w >= 4) ? 64 : 0);
  const int w16o2 = w * 16;

  const u16* gA[2][2]; const u16* gB[2][2];
  #pragma unroll
  for (int h = 0; h < 2; ++h)
    #pragma unroll
    for (int qq = 0; qq < 2; ++qq) {
      gA[h][qq] = A  + (size_t)(bm * 256 + h * 64  + w16o  + qq * 8 + r8) * Ktot + kbase + clog * 8;
      gB[h][qq] = BT + (size_t)(bn * 256 + h * 128 + w16o2 + qq * 8 + r8) * Ktot + kbase + clog * 8;
    }
  u16* sA0 = &sh[0][0][0]; u16* sA1 = &sh[1][0][0];
  u16* sB0 = &sh[0][1][0]; u16* sB1 = &sh[1][1][0];
  const int cks0 = ((0 + lg) ^ (lr & 7)) * 8;
  const int cks1 = ((4 + lg) ^ (lr & 7)) * 8;
  const u16* pA_b0 = sA0 + (wr * 128 + lr) * 64;
  const u16* pA_b1 = sA1 + (wr * 128 + lr) * 64;
  const u16* pB_b0 = sB0 + (wc * 64 + lr) * 64;
  const u16* pB_b1 = sB1 + (wc * 64 + lr) * 64;

  f32x4 acc[2][4][4];
  const f32x4 z4 = { 0.f, 0.f, 0.f, 0.f };
  #pragma unroll
  for (int a = 0; a < 2; ++a)
    #pragma unroll
    for (int b = 0; b < 4; ++b)
      #pragma unroll
      for (int c = 0; c < 4; ++c) acc[a][b][c] = z4;
  short8 af0, af1, af2, af3;
  short8 bf00, bf01, bf02, bf03, bf10, bf11, bf12, bf13;

  // prologue: tile0 -> buf0 (4 halves), tile1 -> buf1 (B0,B1,A0); buf1.A1 staged at first P0
  SG_B(sB0, 0, 0); SG_B(sB0, 1, 0); SG_A(sA0, 0, 0); SG_A(sA0, 1, 0);
  SG_B(sB1, 0, 1); SG_B(sB1, 1, 1); SG_A(sA1, 0, 1);
  GATE6;
  __builtin_amdgcn_s_barrier();

  for (int i = 0; i < NI; ++i) {
    const int k2 = 2 * i;
    const bool st = (i < NI - 1);
    DS_B(pB_b0);
    P_CORE(pA_b0, 0, 0, SG_A(sA1, 1, k2 + 1), HINT8, );
    P_CORE(pA_b0, 1, 0, if (st) SG_B(sB0, 0, k2 + 2), , );
    P_CORE(pA_b0, 0, 1, if (st) SG_B(sB0, 1, k2 + 2), , );
    P_CORE(pA_b0, 1, 1, if (st) SG_A(sA0, 0, k2 + 2), ,
           if (st) { GATE6; } else { GATE0; });
    DS_B(pB_b1);
    P_CORE(pA_b1, 0, 0, if (st) SG_A(sA0, 1, k2 + 2), HINT8, );
    P_CORE(pA_b1, 1, 0, if (st) SG_B(sB1, 0, k2 + 3), , );
    P_CORE(pA_b1, 0, 1, if (st) SG_B(sB1, 1, k2 + 3), , );
    P_CORE(pA_b1, 1, 1, if (st) SG_A(sA1, 0, k2 + 3), ,
           if (st) { GATE6; });
  }

  if constexpr (MODE == 1) {
    float* Co = (float*)C + (size_t)blockIdx.y * M * N;
    #pragma unroll
    for (int mq = 0; mq < 2; ++mq)
      #pragma unroll
      for (int m = 0; m < 4; ++m)
        #pragma unroll
        for (int n = 0; n < 4; ++n)
          #pragma unroll
          for (int rr = 0; rr < 4; ++rr) {
            const int row = bm * 256 + wr * 128 + mq * 64 + m * 16 + lg * 4 + rr;
            const int col = bn * 256 + wc * 64 + n * 16 + lr;
            Co[(size_t)row * N + col] = acc[mq][m][n][rr];
          }
  } else {
    if (bn < 4) {
      u16* Co = (u16*)C; // qbuf, stride 1024
      #pragma unroll
      for (int mq = 0; mq < 2; ++mq)
        #pragma unroll
        for (int m = 0; m < 4; ++m)
          #pragma unroll
          for (int n = 0; n < 4; ++n)
            #pragma unroll
            for (int rr = 0; rr < 4; ++rr) {
              const int row = bm * 256 + wr * 128 + mq * 64 + m * 16 + lg * 4 + rr;
              const int col = bn * 256 + wc * 64 + n * 16 + lr;
              Co[(size_t)row * 1024 + col] = f2bf(acc[mq][m][n][rr]);
            }
    } else {
      u16* Ho = (u16*)C2; // aoh, stride 5120, h starts at col 1024
      const int colb = 1024 + (bn - 4) * 128 + wc * 32 + lr;
      #pragma unroll
      for (int mq = 0; mq < 2; ++mq)
        #pragma unroll
        for (int m = 0; m < 4; ++m)
          #pragma unroll
          for (int rr = 0; rr < 4; ++rr) {
            const int row = bm * 256 + wr * 128 + mq * 64 + m * 16 + lg * 4 + rr;
            #pragma unroll
            for (int n2 = 0; n2 < 2; ++n2) {
              const float a = acc[mq][m][2 * n2][rr];
              const float gt = acc[mq][m][2 * n2 + 1][rr];
              const float h = a * gt / (1.0f + __expf(-gt));
              Ho[(size_t)row * 5120 + colb + n2 * 16] = f2bf(h);
            }
          }
    }
  }
}

// ---------------- split-K GEMM 128x128 (tiny kv projection) ----------------
__global__ __launch_bounds__(256) void gemm_bt_sk(
    const u16* __restrict__ A, const u16* __restrict__ BT, float* __restrict__ Cp,
    int M, int N, int Kslice, int Ktot)
{
  __shared__ u16 As[128 * 32];
  __shared__ u16 Bs[128 * 32];
  const int bm = blockIdx.y, bn = blockIdx.x, z = blockIdx.z;
  const int t = threadIdx.x;
  const int w = t >> 6, lane = t & 63;
  const int wr = w >> 1, wc = w & 1;
  const int lr = lane & 15, lkc = lane >> 4;

  f32x4 acc[4][4];
  const f32x4 z4 = { 0.f, 0.f, 0.f, 0.f };
  #pragma unroll
  for (int mi = 0; mi < 4; ++mi)
    #pragma unroll
    for (int ni = 0; ni < 4; ++ni) acc[mi][ni] = z4;

  const int kbase = z * Kslice;
  const int i0 = t, i1 = t + 256;
  const int r0 = i0 >> 2, k0 = swz4(r0, i0 & 3) * 8;
  const int r1 = i1 >> 2, k1 = swz4(r1, i1 & 3) * 8;
  const u16* a0 = A + (size_t)(bm * 128 + r0) * Ktot + kbase + k0;
  const u16* a1 = A + (size_t)(bm * 128 + r1) * Ktot + kbase + k1;
  const u16* b0 = BT + (size_t)(bn * 128 + r0) * Ktot + kbase + k0;
  const u16* b1 = BT + (size_t)(bn * 128 + r1) * Ktot + kbase + k1;
  u16* As0 = As + (size_t)w * 512;
  u16* As1 = As + (size_t)(w + 4) * 512;
  u16* Bs0 = Bs + (size_t)w * 512;
  u16* Bs1 = Bs + (size_t)(w + 4) * 512;

  const int nk = Kslice >> 5;
  for (int kt = 0; kt < nk; ++kt) {
    __syncthreads();
    GLDS16(a0, As0); GLDS16(a1, As1); GLDS16(b0, Bs0); GLDS16(b1, Bs1);
    a0 += 32; a1 += 32; b0 += 32; b1 += 32;
    __syncthreads();
    short8 af[4], bf[4];
    #pragma unroll
    for (int mi = 0; mi < 4; ++mi) {
      int row = wr * 64 + mi * 16 + lr;
      af[mi] = *(const short8*)&As[row * 32 + swz4(row, lkc) * 8];
    }
    #pragma unroll
    for (int ni = 0; ni < 4; ++ni) {
      int row = wc * 64 + ni * 16 + lr;
      bf[ni] = *(const short8*)&Bs[row * 32 + swz4(row, lkc) * 8];
    }
    #pragma unroll
    for (int mi = 0; mi < 4; ++mi)
      #pragma unroll
      for (int ni = 0; ni < 4; ++ni)
        acc[mi][ni] = __builtin_amdgcn_mfma_f32_16x16x32_bf16(af[mi], bf[ni], acc[mi][ni], 0, 0, 0);
  }

  float* Cz = Cp + (size_t)z * M * N;
  const int row0 = bm * 128 + wr * 64, col0 = bn * 128 + wc * 64;
  const int rsub = (lane >> 4) * 4;
  #pragma unroll
  for (int mi = 0; mi < 4; ++mi)
    #pragma unroll
    for (int ni = 0; ni < 4; ++ni)
      #pragma unroll
      for (int r = 0; r < 4; ++r)
        Cz[(size_t)(row0 + mi * 16 + rsub + r) * N + (col0 + ni * 16 + lr)] = acc[mi][ni][r];
}

// ---------------- reduce 8 f32 partials (4096x128) -> bf16 ----------------
__global__ __launch_bounds__(256) void reduce_kv(const float* __restrict__ part, u16* __restrict__ out)
{
  const size_t base = ((size_t)blockIdx.x * 256 + threadIdx.x) * 4;
  f32x4 s = *(const f32x4*)&part[base];
  #pragma unroll
  for (int zz = 1; zz < 8; ++zz) {
    const f32x4 v = *(const f32x4*)&part[(size_t)zz * 524288 + base];
    s[0] += v[0]; s[1] += v[1]; s[2] += v[2]; s[3] += v[3];
  }
  uint2 pv;
  pv.x = (unsigned)f2bf(s[0]) | ((unsigned)f2bf(s[1]) << 16);
  pv.y = (unsigned)f2bf(s[2]) | ((unsigned)f2bf(s[3]) << 16);
  *(uint2*)&out[base] = pv;
}

// ---------------- out = sum of 4 f32 partials (4096x1024) ----------------
__global__ __launch_bounds__(256) void reduce_out(const float* __restrict__ part, float* __restrict__ out)
{
  const size_t base = ((size_t)blockIdx.x * 256 + threadIdx.x) * 4;
  f32x4 s = *(const f32x4*)&part[base];
  #pragma unroll
  for (int zz = 1; zz < 4; ++zz) {
    const f32x4 v = *(const f32x4*)&part[(size_t)zz * 4194304 + base];
    s[0] += v[0]; s[1] += v[1]; s[2] += v[2]; s[3] += v[3];
  }
  *(f32x4*)&out[base] = s;
}

// ---------------- flash cross-attention (multi-query: 1 KV head) ----------------
// q: qbuf (B*N,1024) bf16 pre-scaled; kv: (B*J,128) bf16; o -> aoh cols 0..1023 (stride 5120)
__global__ __launch_bounds__(256) void attn_kernel(
    const u16* __restrict__ q, const u16* __restrict__ kv, u16* __restrict__ o)
{
  __shared__ u16 Ks[128 * 64];
  __shared__ u16 Vt[64 * 128];
  __shared__ u16 Ps[4][32 * 128];
  const int b = blockIdx.z, hb = blockIdx.y, qb = blockIdx.x;
  const int t = threadIdx.x, w = t >> 6, lane = t & 63;
  const int q32 = lane & 31, hl = lane >> 5;
  const int hd = hb * 4 + w;

  const size_t qbase = (size_t)b * 2048 + qb * 64;
  short8 qa[2][4];
  #pragma unroll
  for (int t32 = 0; t32 < 2; ++t32)
    #pragma unroll
    for (int dq = 0; dq < 4; ++dq)
      qa[t32][dq] = *(const short8*)&q[(qbase + t32 * 32 + q32) * 1024 + hd * 64 + dq * 16 + hl * 8];

  f32x16 oacc[2][2];
  #pragma unroll
  for (int i = 0; i < 2; ++i)
    #pragma unroll
    for (int j = 0; j < 2; ++j)
      #pragma unroll
      for (int r = 0; r < 16; ++r) oacc[i][j][r] = 0.f;
  float m_[2] = { -1e30f, -1e30f }, l_[2] = { 0.f, 0.f };

  const size_t kvb = (size_t)b * 2048 * 128;
  const int vd0 = (t & 7) * 8;
  const int vodd = (t >> 3) & 1;
  u16* Pw = &Ps[w][0];

  for (int jt = 0; jt < 16; ++jt) {
    __syncthreads();
    #pragma unroll
    for (int n = 0; n < 4; ++n) {
      const int cc = n * 256 + w * 64;
      const int ccl = cc + lane;
      const int row = ccl >> 3, lc = (ccl & 7) ^ (row & 7);
      GLDS16(&kv[kvb + (size_t)(jt * 128 + row) * 128 + lc * 8], Ks + (size_t)cc * 8);
    }
    #pragma unroll
    for (int c = 0; c < 4; ++c) {
      const int seg = c * 256 + t;
      const int vj = seg >> 3;
      const int jp = vj >> 1;
      const uint4 vv = *(const uint4*)&kv[kvb + (size_t)(jt * 128 + vj) * 128 + 64 + vd0];
      uint4 pvv;
      pvv.x = __shfl_xor((int)vv.x, 8);
      pvv.y = __shfl_xor((int)vv.y, 8);
      pvv.z = __shfl_xor((int)vv.z, 8);
      pvv.w = __shfl_xor((int)vv.w, 8);
      const unsigned ow[4] = { vv.x, vv.y, vv.z, vv.w };
      const unsigned pw[4] = { pvv.x, pvv.y, pvv.z, pvv.w };
      if (!vodd) {
        #pragma unroll
        for (int u = 0; u < 4; ++u) {
          const int d = vd0 + u;
          const unsigned own = (u & 1) ? (ow[u >> 1] >> 16) : (ow[u >> 1] & 0xffffu);
          const unsigned par = (u & 1) ? (pw[u >> 1] >> 16) : (pw[u >> 1] & 0xffffu);
          const int byteoff = d * 256 + ((4 * jp) ^ (((d & 7) ^ ((d >> 3) & 7)) << 4));
          *(unsigned*)((char*)Vt + byteoff) = own | (par << 16);
        }
      } else {
        #pragma unroll
        for (int u = 0; u < 4; ++u) {
          const int ue = u + 4;
          const int d = vd0 + ue;
          const unsigned own = (ue & 1) ? (ow[ue >> 1] >> 16) : (ow[ue >> 1] & 0xffffu);
          const unsigned par = (ue & 1) ? (pw[ue >> 1] >> 16) : (pw[ue >> 1] & 0xffffu);
          const int byteoff = d * 256 + ((4 * jp) ^ (((d & 7) ^ ((d >> 3) & 7)) << 4));
          *(unsigned*)((char*)Vt + byteoff) = par | (own << 16);
        }
      }
    }
    __syncthreads();

    #pragma unroll
    for (int t32 = 0; t32 < 2; ++t32) {
      f32x16 s[4];
      #pragma unroll
      for (int j32 = 0; j32 < 4; ++j32)
        #pragma unroll
        for (int r = 0; r < 16; ++r) s[j32][r] = 0.f;
      #pragma unroll
      for (int j32 = 0; j32 < 4; ++j32) {
        const int row = j32 * 32 + q32;
        #pragma unroll
        for (int dq = 0; dq < 4; ++dq) {
          const int slot = (dq * 2 + hl) ^ (row & 7);
          const short8 kf = *(const short8*)&Ks[row * 64 + slot * 8];
          s[j32] = __builtin_amdgcn_mfma_f32_32x32x16_bf16(kf, qa[t32][dq], s[j32], 0, 0, 0);
        }
      }
      float mt = -1e30f;
      #pragma unroll
      for (int j32 = 0; j32 < 4; ++j32)
        #pragma unroll
        for (int r = 0; r < 16; ++r) mt = fmaxf(mt, s[j32][r]);
      mt = fmaxf(mt, __shfl_xor(mt, 32));
      const float nm = fmaxf(m_[t32], mt);
      const float alpha = __expf(m_[t32] - nm);
      m_[t32] = nm;
      float lsum = 0.f;
      #pragma unroll
      for (int j32 = 0; j32 < 4; ++j32) {
        float p[16];
        #pragma unroll
        for (int r = 0; r < 16; ++r) { p[r] = __expf(s[j32][r] - nm); lsum += p[r]; }
        #pragma unroll
        for (int g = 0; g < 4; ++g) {
          const unsigned lo = cvtpk(p[4 * g + 0], p[4 * g + 1]);
          const unsigned hi = cvtpk(p[4 * g + 2], p[4 * g + 3]);
          const int j2 = j32 * 64 + 16 * g + 8 * hl;
          const int byteoff = q32 * 256 + (j2 ^ ((q32 & 7) << 4));
          uint2 wv; wv.x = lo; wv.y = hi;
          *(uint2*)((char*)Pw + byteoff) = wv;
        }
      }
      lsum += __shfl_xor(lsum, 32);
      l_[t32] = l_[t32] * alpha + lsum;
      #pragma unroll
      for (int d32 = 0; d32 < 2; ++d32)
        #pragma unroll
        for (int r = 0; r < 16; ++r) oacc[t32][d32][r] *= alpha;
      short8 pf[8];
      #pragma unroll
      for (int kk = 0; kk < 8; ++kk) {
        const int byteoff = q32 * 256 + ((kk * 32 + hl * 16) ^ ((q32 & 7) << 4));
        pf[kk] = *(const short8*)((const char*)Pw + byteoff);
      }
      #pragma unroll
      for (int d32 = 0; d32 < 2; ++d32) {
        const int dr = d32 * 32 + q32;
        const int vswz = ((dr & 7) ^ ((dr >> 3) & 7)) << 4;
        #pragma unroll
        for (int kk = 0; kk < 8; ++kk) {
          const int byteoff = dr * 256 + ((kk * 32 + hl * 16) ^ vswz);
          const short8 vf = *(const short8*)((const char*)Vt + byteoff);
          oacc[t32][d32] = __builtin_amdgcn_mfma_f32_32x32x16_bf16(vf, pf[kk], oacc[t32][d32], 0, 0, 0);
        }
      }
    }
  }

  float* Ot = (float*)Pw;
  #pragma unroll
  for (int t32 = 0; t32 < 2; ++t32) {
    const float inv = 1.0f / l_[t32];
    #pragma unroll
    for (int d32 = 0; d32 < 2; ++d32) {
      #pragma unroll
      for (int r = 0; r < 16; ++r) {
        const int d = (r & 3) + 8 * (r >> 2) + 4 * hl;
        const int byteoff = q32 * 128 + ((4 * d) ^ ((q32 & 7) << 4));
        *(float*)((char*)Ot + byteoff) = oacc[t32][d32][r] * inv;
      }
      const int qr = lane >> 1, dc = (lane & 1) * 16;
      union { u16 s[16]; uint4 v[2]; } ob;
      #pragma unroll
      for (int cch = 0; cch < 4; ++cch) {
        const int byteoff = qr * 128 + ((4 * (dc + 4 * cch)) ^ ((qr & 7) << 4));
        const f32x4 vv = *(const f32x4*)((const char*)Ot + byteoff);
        ob.s[cch * 4 + 0] = f2bf(vv[0]);
        ob.s[cch * 4 + 1] = f2bf(vv[1]);
        ob.s[cch * 4 + 2] = f2bf(vv[2]);
        ob.s[cch * 4 + 3] = f2bf(vv[3]);
      }
      u16* orow = &o[(qbase + t32 * 32 + qr) * 5120 + hd * 64 + d32 * 32 + dc];
      *(uint4*)orow = ob.v[0];
      *(uint4*)(orow + 8) = ob.v[1];
    }
  }
}

extern "C" void kernel_launch(void* const* d_in, const int* in_sizes, int n_in,
                              void* d_out, int out_size, void* d_ws, size_t ws_size,
                              hipStream_t stream)
{
  const float* x    = (const float*)d_in[0];
  const float* ctx  = (const float*)d_in[1];
  const float* ng   = (const float*)d_in[2];
  const float* nb   = (const float*)d_in[3];
  const float* cg   = (const float*)d_in[4];
  const float* cb   = (const float*)d_in[5];
  const float* Wq   = (const float*)d_in[6];
  const float* Wkv  = (const float*)d_in[7];
  const float* Wo   = (const float*)d_in[8];
  const float* Wff1 = (const float*)d_in[9];
  const float* Wff2 = (const float*)d_in[10];

  u16* p = (u16*)d_ws;
  u16* W1T   = p; p += (size_t)9216 * 1024;   // [Wq*0.125 | Wff1 interleaved]^T
  u16* WkvT  = p; p += (size_t)128 * 1024;
  u16* WcT   = p; p += (size_t)1024 * 5120;   // [Wo ; Wff2]^T
  u16* kvbuf = p; p += (size_t)4096 * 128;
  u16* aoh   = p; p += (size_t)4096 * 5120;   // [attn_out | h]
  u16* xn    = p; p += (size_t)4096 * 1024;
  u16* cn    = p; p += (size_t)4096 * 1024;
  u16* qbuf  = p; p += (size_t)4096 * 1024;
  float* kvpart = (float*)W1T;                 // 16 MB over W1T (dead after qff GEMM)
  float* ffpart = (float*)xn;                  // 64 MB over xn|cn|qbuf + tail (all dead by final GEMM)
  (void)in_sizes; (void)n_in; (void)out_size; (void)ws_size;

  ln_kernel<<<8192, 256, 0, stream>>>(x, ctx, ng, nb, cg, cb, xn, cn);

  transpose_k<<<dim3(16, 16),  256, 0, stream>>>(Wq,   W1T,        1024, 1024, 1024, 0.125f);
  transpose_ff1<<<dim3(128, 16), 256, 0, stream>>>(Wff1, W1T);
  transpose_k<<<dim3(2, 16),   256, 0, stream>>>(Wkv,  WkvT,       1024, 128,  1024, 1.0f);
  transpose_k<<<dim3(16, 16),  256, 0, stream>>>(Wo,   WcT,        1024, 1024, 5120, 1.0f);
  transpose_k<<<dim3(16, 64),  256, 0, stream>>>(Wff2, WcT + 1024, 4096, 1024, 5120, 1.0f);

  // fused: qbuf = xn@Wq*scale ; aoh[:,1024:] = silu epilogue of xn@Wff1 (4096x9216x1024)
  gemm8p<2><<<dim3(576), 512, 0, stream>>>(xn, W1T, qbuf, aoh, 4096, 9216, 1024, 1024);
  // kv = cn @ Wkv, split-K 8 (partials over dead W1T), reduce to bf16
  gemm_bt_sk<<<dim3(1, 32, 8), 256, 0, stream>>>(cn, WkvT, kvpart, 4096, 128, 128, 1024);
  reduce_kv<<<512, 256, 0, stream>>>(kvpart, kvbuf);
  // attention -> aoh[:,0:1024]
  attn_kernel<<<dim3(32, 4, 2), 256, 0, stream>>>(qbuf, kvbuf, aoh);
  // out = aoh @ [Wo ; Wff2]  (4096x1024x5120), split-K 4, f32 partials over dead xn/cn/qbuf
  gemm8p<1><<<dim3(64, 4), 512, 0, stream>>>(aoh, WcT, ffpart, nullptr, 4096, 1024, 5120, 1280);
  reduce_out<<<4096, 256, 0, stream>>>(ffpart, (float*)d_out);
}